// Round 3
// baseline (337.520 us; speedup 1.0000x reference)
//
#include <hip/hip_runtime.h>

// GCN 2-layer: x[N,128] -> GCNConv(W1[128,64]) -> relu -> GCNConv(W2[64,32])
// out[d] = dis[d] * (g[d] + sum_{e: dst=d} g[src]) + b,  g = (x@W)*dis.
// R2: wave-uniform scalar col loads + 8-deep unrolled gathers (ILP),
//     float4 LDS reads in gemms, deg via memset (in-degree).

#define F_IN 128
#define F_MID 64
#define F_OUT 32
#define SCAN_B 256

#define RFL(x) __builtin_amdgcn_readfirstlane(x)

__global__ void k_deg_edges(const int* __restrict__ dst, int E, int* __restrict__ deg) {
    int e = blockIdx.x * blockDim.x + threadIdx.x;
    if (e < E) atomicAdd(&deg[dst[e]], 1);
}

// ---- 3-phase exclusive scan of in-degree -> rowstart, cursor; also dis ----
__global__ __launch_bounds__(SCAN_B) void k_scan_partial(
    const int* __restrict__ deg, int n, int* __restrict__ bsum) {
    __shared__ int s[SCAN_B];
    int i = blockIdx.x * SCAN_B + threadIdx.x;
    s[threadIdx.x] = (i < n) ? deg[i] : 0;
    __syncthreads();
    for (int o = SCAN_B / 2; o > 0; o >>= 1) {
        if (threadIdx.x < o) s[threadIdx.x] += s[threadIdx.x + o];
        __syncthreads();
    }
    if (threadIdx.x == 0) bsum[blockIdx.x] = s[0];
}

__global__ __launch_bounds__(SCAN_B) void k_scan_bsums(int* __restrict__ bsum, int nb) {
    __shared__ int s[SCAN_B];
    int t = threadIdx.x;
    int v = (t < nb) ? bsum[t] : 0;
    s[t] = v;
    __syncthreads();
    for (int o = 1; o < SCAN_B; o <<= 1) {
        int add = (t >= o) ? s[t - o] : 0;
        __syncthreads();
        s[t] += add;
        __syncthreads();
    }
    if (t < nb) bsum[t] = s[t] - v;  // exclusive
}

__global__ __launch_bounds__(SCAN_B) void k_scan_final(
    const int* __restrict__ deg, int n, const int* __restrict__ bsum,
    int* __restrict__ rowstart, int* __restrict__ cursor, float* __restrict__ dis) {
    __shared__ int s[SCAN_B];
    int i = blockIdx.x * SCAN_B + threadIdx.x;
    int t = threadIdx.x;
    int v = (i < n) ? deg[i] : 0;
    s[t] = v;
    __syncthreads();
    for (int o = 1; o < SCAN_B; o <<= 1) {
        int add = (t >= o) ? s[t - o] : 0;
        __syncthreads();
        s[t] += add;
        __syncthreads();
    }
    if (i < n) {
        int ex = s[t] - v + bsum[blockIdx.x];
        rowstart[i] = ex;
        cursor[i] = ex;
        dis[i] = rsqrtf((float)(v + 1));  // +1 self-loop
    }
}

__global__ void k_fill(const int* __restrict__ src, const int* __restrict__ dst,
                       int E, int* __restrict__ cursor, int* __restrict__ col) {
    int e = blockIdx.x * blockDim.x + threadIdx.x;
    if (e < E) {
        int d = dst[e];
        int pos = atomicAdd(&cursor[d], 1);
        col[pos] = src[e];
    }
}

// g1[r,f] = (x[r,:] @ W1[:,f]) * dis[r]
__global__ __launch_bounds__(256) void k_gemm1(
    const float* __restrict__ x, const float* __restrict__ W1,
    const float* __restrict__ dis, float* __restrict__ g1, int n) {
    __shared__ float Ws[F_IN * F_MID];   // 32 KB, Ws[k][f]
    __shared__ float xs[16][F_IN];       // 8 KB
    int tid = threadIdx.x;
    for (int i = tid; i < F_IN * F_MID; i += 256) Ws[i] = W1[i];
    int row0 = blockIdx.x * 16;
    for (int i = tid; i < 16 * F_IN; i += 256) {
        int r = row0 + (i >> 7);
        xs[i >> 7][i & 127] = (r < n) ? x[(size_t)r * F_IN + (i & 127)] : 0.0f;
    }
    __syncthreads();
    int f  = tid & 63;
    int rs = tid >> 6;
    float acc0 = 0.f, acc1 = 0.f, acc2 = 0.f, acc3 = 0.f;
    for (int k = 0; k < F_IN; k += 4) {
        float4 x0 = *(const float4*)&xs[rs * 4 + 0][k];
        float4 x1 = *(const float4*)&xs[rs * 4 + 1][k];
        float4 x2 = *(const float4*)&xs[rs * 4 + 2][k];
        float4 x3 = *(const float4*)&xs[rs * 4 + 3][k];
        float w0 = Ws[(k + 0) * F_MID + f];
        float w1 = Ws[(k + 1) * F_MID + f];
        float w2 = Ws[(k + 2) * F_MID + f];
        float w3 = Ws[(k + 3) * F_MID + f];
        acc0 += x0.x * w0 + x0.y * w1 + x0.z * w2 + x0.w * w3;
        acc1 += x1.x * w0 + x1.y * w1 + x1.z * w2 + x1.w * w3;
        acc2 += x2.x * w0 + x2.y * w1 + x2.z * w2 + x2.w * w3;
        acc3 += x3.x * w0 + x3.y * w1 + x3.z * w2 + x3.w * w3;
    }
    float accs[4] = {acc0, acc1, acc2, acc3};
#pragma unroll
    for (int j = 0; j < 4; ++j) {
        int r = row0 + rs * 4 + j;
        if (r < n) g1[(size_t)r * F_MID + f] = accs[j] * dis[r];
    }
}

// one wave per dst row; 8 gathers in flight; col via wave-uniform scalar loads
__global__ __launch_bounds__(256) void k_gather1(
    const int* __restrict__ rowstart, const int* __restrict__ deg,
    const int* __restrict__ col, const float* __restrict__ g1,
    const float* __restrict__ dis, const float* __restrict__ b1,
    float* __restrict__ h, int n) {
    int wave = RFL(threadIdx.x >> 6);
    int f    = threadIdx.x & 63;
    int d    = blockIdx.x * 4 + wave;
    if (d >= n) return;
    int base = RFL(rowstart[d]);
    int cnt  = RFL(deg[d]);
    float a0 = g1[(size_t)d * F_MID + f];  // self-loop
    float a1 = 0.f, a2 = 0.f, a3 = 0.f, a4 = 0.f, a5 = 0.f, a6 = 0.f, a7 = 0.f;
    int j = 0;
    for (; j + 8 <= cnt; j += 8) {
        int s0 = col[base + j + 0], s1 = col[base + j + 1];
        int s2 = col[base + j + 2], s3 = col[base + j + 3];
        int s4 = col[base + j + 4], s5 = col[base + j + 5];
        int s6 = col[base + j + 6], s7 = col[base + j + 7];
        a0 += g1[(size_t)s0 * F_MID + f];
        a1 += g1[(size_t)s1 * F_MID + f];
        a2 += g1[(size_t)s2 * F_MID + f];
        a3 += g1[(size_t)s3 * F_MID + f];
        a4 += g1[(size_t)s4 * F_MID + f];
        a5 += g1[(size_t)s5 * F_MID + f];
        a6 += g1[(size_t)s6 * F_MID + f];
        a7 += g1[(size_t)s7 * F_MID + f];
    }
    for (; j + 4 <= cnt; j += 4) {
        int s0 = col[base + j + 0], s1 = col[base + j + 1];
        int s2 = col[base + j + 2], s3 = col[base + j + 3];
        a0 += g1[(size_t)s0 * F_MID + f];
        a1 += g1[(size_t)s1 * F_MID + f];
        a2 += g1[(size_t)s2 * F_MID + f];
        a3 += g1[(size_t)s3 * F_MID + f];
    }
    for (; j < cnt; ++j) a0 += g1[(size_t)col[base + j] * F_MID + f];
    float acc = ((a0 + a1) + (a2 + a3)) + ((a4 + a5) + (a6 + a7));
    h[(size_t)d * F_MID + f] = fmaxf(acc * dis[d] + b1[f], 0.0f);
}

// g2[r,j] = (h[r,:] @ W2[:,j]) * dis[r]
__global__ __launch_bounds__(256) void k_gemm2(
    const float* __restrict__ h, const float* __restrict__ W2,
    const float* __restrict__ dis, float* __restrict__ g2, int n) {
    __shared__ float Ws[F_MID * F_OUT];  // 8 KB, Ws[k][j]
    __shared__ float hs[8][F_MID];       // 2 KB
    int tid = threadIdx.x;
    for (int i = tid; i < F_MID * F_OUT; i += 256) Ws[i] = W2[i];
    int row0 = blockIdx.x * 8;
    for (int i = tid; i < 8 * F_MID; i += 256) {
        int r = row0 + (i >> 6);
        hs[i >> 6][i & 63] = (r < n) ? h[(size_t)r * F_MID + (i & 63)] : 0.0f;
    }
    __syncthreads();
    int j  = tid & 31;
    int rs = tid >> 5;
    float acc = 0.0f;
    for (int k = 0; k < F_MID; k += 4) {
        float4 hv = *(const float4*)&hs[rs][k];
        acc += hv.x * Ws[(k + 0) * F_OUT + j];
        acc += hv.y * Ws[(k + 1) * F_OUT + j];
        acc += hv.z * Ws[(k + 2) * F_OUT + j];
        acc += hv.w * Ws[(k + 3) * F_OUT + j];
    }
    int r = row0 + rs;
    if (r < n) g2[(size_t)r * F_OUT + j] = acc * dis[r];
}

// one wave per dst row: lanes = 32 features x 2 neighbor slots; shfl_xor(32) combine
__global__ __launch_bounds__(256) void k_gather2(
    const int* __restrict__ rowstart, const int* __restrict__ deg,
    const int* __restrict__ col, const float* __restrict__ g2,
    const float* __restrict__ dis, const float* __restrict__ b2,
    float* __restrict__ out, int n) {
    int wave = RFL(threadIdx.x >> 6);
    int lane = threadIdx.x & 63;
    int j    = lane & 31;   // feature
    int p    = lane >> 5;   // neighbor slot 0/1
    int d    = blockIdx.x * 4 + wave;
    if (d >= n) return;
    int base = RFL(rowstart[d]);
    int cnt  = RFL(deg[d]);
    float a0 = (p == 0) ? g2[(size_t)d * F_OUT + j] : 0.0f;  // self-loop
    float a1 = 0.f, a2 = 0.f, a3 = 0.f;
    int t = 0;
    for (; t + 8 <= cnt; t += 8) {
        int sA0 = col[base + t + 0], sA1 = col[base + t + 1];
        int sB0 = col[base + t + 2], sB1 = col[base + t + 3];
        int sC0 = col[base + t + 4], sC1 = col[base + t + 5];
        int sD0 = col[base + t + 6], sD1 = col[base + t + 7];
        int sA = p ? sA1 : sA0;
        int sB = p ? sB1 : sB0;
        int sC = p ? sC1 : sC0;
        int sD = p ? sD1 : sD0;
        a0 += g2[(size_t)sA * F_OUT + j];
        a1 += g2[(size_t)sB * F_OUT + j];
        a2 += g2[(size_t)sC * F_OUT + j];
        a3 += g2[(size_t)sD * F_OUT + j];
    }
    for (; t + 2 <= cnt; t += 2) {
        int s0 = col[base + t], s1 = col[base + t + 1];
        int s = p ? s1 : s0;
        a0 += g2[(size_t)s * F_OUT + j];
    }
    if (t < cnt) {  // odd leftover: slot 0 only
        int s = col[base + t];
        if (p == 0) a0 += g2[(size_t)s * F_OUT + j];
    }
    float acc = (a0 + a1) + (a2 + a3);
    acc += __shfl_xor(acc, 32);
    if (p == 0) out[(size_t)d * F_OUT + j] = acc * dis[d] + b2[j];
}

extern "C" void kernel_launch(void* const* d_in, const int* in_sizes, int n_in,
                              void* d_out, int out_size, void* d_ws, size_t ws_size,
                              hipStream_t stream) {
    const float* x  = (const float*)d_in[0];
    const int*   ei = (const int*)d_in[1];
    const float* W1 = (const float*)d_in[2];
    const float* b1 = (const float*)d_in[3];
    const float* W2 = (const float*)d_in[4];
    const float* b2 = (const float*)d_in[5];

    int n = in_sizes[0] / F_IN;   // 50000
    int E = in_sizes[1] / 2;      // 800000
    const int* src = ei;
    const int* dst = ei + E;

    char* ws = (char*)d_ws;
    size_t off = 0;
    auto alloc = [&](size_t bytes) {
        char* p = ws + off;
        off += (bytes + 255) & ~(size_t)255;
        return p;
    };
    int*   deg      = (int*)  alloc((size_t)n * 4);   // in-degree (no self-loop)
    float* dis      = (float*)alloc((size_t)n * 4);
    int*   rowstart = (int*)  alloc((size_t)n * 4);
    int*   cursor   = (int*)  alloc((size_t)n * 4);
    int*   bsum     = (int*)  alloc((size_t)SCAN_B * 4);
    int*   col      = (int*)  alloc((size_t)E * 4);
    float* g1       = (float*)alloc((size_t)n * F_MID * 4);
    float* h        = (float*)alloc((size_t)n * F_MID * 4);
    float* g2       = (float*)alloc((size_t)n * F_OUT * 4);

    int B = 256;
    int nb = (n + SCAN_B - 1) / SCAN_B;  // 196 < SCAN_B (k_scan_bsums requirement)

    hipMemsetAsync(deg, 0, (size_t)n * 4, stream);
    k_deg_edges<<<(E + B - 1) / B, B, 0, stream>>>(dst, E, deg);

    k_scan_partial<<<nb, SCAN_B, 0, stream>>>(deg, n, bsum);
    k_scan_bsums<<<1, SCAN_B, 0, stream>>>(bsum, nb);
    k_scan_final<<<nb, SCAN_B, 0, stream>>>(deg, n, bsum, rowstart, cursor, dis);

    k_fill<<<(E + B - 1) / B, B, 0, stream>>>(src, dst, E, cursor, col);

    k_gemm1<<<(n + 15) / 16, 256, 0, stream>>>(x, W1, dis, g1, n);
    k_gather1<<<(n + 3) / 4, 256, 0, stream>>>(rowstart, deg, col, g1, dis, b1, h, n);
    k_gemm2<<<(n + 7) / 8, 256, 0, stream>>>(h, W2, dis, g2, n);
    k_gather2<<<(n + 3) / 4, 256, 0, stream>>>(rowstart, deg, col, g2, dis, b2,
                                               (float*)d_out, n);
}

// Round 4
// 254.923 us; speedup vs baseline: 1.3240x; 1.3240x over previous
//
#include <hip/hip_runtime.h>

// GCN 2-layer: x[N,128] -> GCNConv(W1[128,64]) -> relu -> GCNConv(W2[64,32])
// out[d] = dis[d] * (g[d] + sum_{e: dst=d} g[src]) + b,  g = (x@W)*dis.
// R3: gemms rewritten lane=row / wave=feature-slice: W operand wave-uniform
//     (s_load), x via conflict-free padded LDS, 16 FMA per LDS read.

#define F_IN 128
#define F_MID 64
#define F_OUT 32
#define SCAN_B 256

#define RFL(x) __builtin_amdgcn_readfirstlane(x)

__global__ void k_deg_edges(const int* __restrict__ dst, int E, int* __restrict__ deg) {
    int e = blockIdx.x * blockDim.x + threadIdx.x;
    if (e < E) atomicAdd(&deg[dst[e]], 1);
}

// ---- 3-phase exclusive scan of in-degree -> rowstart, cursor; also dis ----
__global__ __launch_bounds__(SCAN_B) void k_scan_partial(
    const int* __restrict__ deg, int n, int* __restrict__ bsum) {
    __shared__ int s[SCAN_B];
    int i = blockIdx.x * SCAN_B + threadIdx.x;
    s[threadIdx.x] = (i < n) ? deg[i] : 0;
    __syncthreads();
    for (int o = SCAN_B / 2; o > 0; o >>= 1) {
        if (threadIdx.x < o) s[threadIdx.x] += s[threadIdx.x + o];
        __syncthreads();
    }
    if (threadIdx.x == 0) bsum[blockIdx.x] = s[0];
}

__global__ __launch_bounds__(SCAN_B) void k_scan_bsums(int* __restrict__ bsum, int nb) {
    __shared__ int s[SCAN_B];
    int t = threadIdx.x;
    int v = (t < nb) ? bsum[t] : 0;
    s[t] = v;
    __syncthreads();
    for (int o = 1; o < SCAN_B; o <<= 1) {
        int add = (t >= o) ? s[t - o] : 0;
        __syncthreads();
        s[t] += add;
        __syncthreads();
    }
    if (t < nb) bsum[t] = s[t] - v;  // exclusive
}

__global__ __launch_bounds__(SCAN_B) void k_scan_final(
    const int* __restrict__ deg, int n, const int* __restrict__ bsum,
    int* __restrict__ rowstart, int* __restrict__ cursor, float* __restrict__ dis) {
    __shared__ int s[SCAN_B];
    int i = blockIdx.x * SCAN_B + threadIdx.x;
    int t = threadIdx.x;
    int v = (i < n) ? deg[i] : 0;
    s[t] = v;
    __syncthreads();
    for (int o = 1; o < SCAN_B; o <<= 1) {
        int add = (t >= o) ? s[t - o] : 0;
        __syncthreads();
        s[t] += add;
        __syncthreads();
    }
    if (i < n) {
        int ex = s[t] - v + bsum[blockIdx.x];
        rowstart[i] = ex;
        cursor[i] = ex;
        dis[i] = rsqrtf((float)(v + 1));  // +1 self-loop
    }
}

__global__ void k_fill(const int* __restrict__ src, const int* __restrict__ dst,
                       int E, int* __restrict__ cursor, int* __restrict__ col) {
    int e = blockIdx.x * blockDim.x + threadIdx.x;
    if (e < E) {
        int d = dst[e];
        int pos = atomicAdd(&cursor[d], 1);
        col[pos] = src[e];
    }
}

// g1[r,f] = (x[r,:] @ W1[:,f]) * dis[r]
// lane = row (64 rows/block), wave w -> features [16w, 16w+16)
__global__ __launch_bounds__(256, 4) void k_gemm1(
    const float* __restrict__ x, const float* __restrict__ W1,
    const float* __restrict__ dis, float* __restrict__ g1, int n) {
    __shared__ float xs[64 * 129];   // pad 129: bank (r+k)%32, conflict-free
    int tid  = threadIdx.x;
    int row0 = blockIdx.x * 64;
    for (int i = tid; i < 64 * F_IN; i += 256) {
        int r = i >> 7, k = i & 127;
        int gr = row0 + r;
        xs[r * 129 + k] = (gr < n) ? x[(size_t)gr * F_IN + k] : 0.0f;
    }
    __syncthreads();
    int w = RFL(tid >> 6);   // wave id 0..3 (uniform -> W loads become s_load)
    int r = tid & 63;        // row lane
    const float4* W4 = (const float4*)W1;   // [128][16] float4 view
    float4 a0 = {0.f,0.f,0.f,0.f}, a1 = a0, a2 = a0, a3 = a0;
#pragma unroll 4
    for (int k = 0; k < F_IN; ++k) {
        float xv = xs[r * 129 + k];
        float4 w0 = W4[k * 16 + w * 4 + 0];
        float4 w1 = W4[k * 16 + w * 4 + 1];
        float4 w2 = W4[k * 16 + w * 4 + 2];
        float4 w3 = W4[k * 16 + w * 4 + 3];
        a0.x += xv * w0.x; a0.y += xv * w0.y; a0.z += xv * w0.z; a0.w += xv * w0.w;
        a1.x += xv * w1.x; a1.y += xv * w1.y; a1.z += xv * w1.z; a1.w += xv * w1.w;
        a2.x += xv * w2.x; a2.y += xv * w2.y; a2.z += xv * w2.z; a2.w += xv * w2.w;
        a3.x += xv * w3.x; a3.y += xv * w3.y; a3.z += xv * w3.z; a3.w += xv * w3.w;
    }
    int gr = row0 + r;
    if (gr < n) {
        float dv = dis[gr];
        a0.x *= dv; a0.y *= dv; a0.z *= dv; a0.w *= dv;
        a1.x *= dv; a1.y *= dv; a1.z *= dv; a1.w *= dv;
        a2.x *= dv; a2.y *= dv; a2.z *= dv; a2.w *= dv;
        a3.x *= dv; a3.y *= dv; a3.z *= dv; a3.w *= dv;
        float4* o4 = (float4*)&g1[(size_t)gr * F_MID + w * 16];
        o4[0] = a0; o4[1] = a1; o4[2] = a2; o4[3] = a3;
    }
}

// one wave per dst row; 8 gathers in flight; col via wave-uniform scalar loads
__global__ __launch_bounds__(256) void k_gather1(
    const int* __restrict__ rowstart, const int* __restrict__ deg,
    const int* __restrict__ col, const float* __restrict__ g1,
    const float* __restrict__ dis, const float* __restrict__ b1,
    float* __restrict__ h, int n) {
    int wave = RFL(threadIdx.x >> 6);
    int f    = threadIdx.x & 63;
    int d    = blockIdx.x * 4 + wave;
    if (d >= n) return;
    int base = RFL(rowstart[d]);
    int cnt  = RFL(deg[d]);
    float a0 = g1[(size_t)d * F_MID + f];  // self-loop
    float a1 = 0.f, a2 = 0.f, a3 = 0.f, a4 = 0.f, a5 = 0.f, a6 = 0.f, a7 = 0.f;
    int j = 0;
    for (; j + 8 <= cnt; j += 8) {
        int s0 = col[base + j + 0], s1 = col[base + j + 1];
        int s2 = col[base + j + 2], s3 = col[base + j + 3];
        int s4 = col[base + j + 4], s5 = col[base + j + 5];
        int s6 = col[base + j + 6], s7 = col[base + j + 7];
        a0 += g1[(size_t)s0 * F_MID + f];
        a1 += g1[(size_t)s1 * F_MID + f];
        a2 += g1[(size_t)s2 * F_MID + f];
        a3 += g1[(size_t)s3 * F_MID + f];
        a4 += g1[(size_t)s4 * F_MID + f];
        a5 += g1[(size_t)s5 * F_MID + f];
        a6 += g1[(size_t)s6 * F_MID + f];
        a7 += g1[(size_t)s7 * F_MID + f];
    }
    for (; j + 4 <= cnt; j += 4) {
        int s0 = col[base + j + 0], s1 = col[base + j + 1];
        int s2 = col[base + j + 2], s3 = col[base + j + 3];
        a0 += g1[(size_t)s0 * F_MID + f];
        a1 += g1[(size_t)s1 * F_MID + f];
        a2 += g1[(size_t)s2 * F_MID + f];
        a3 += g1[(size_t)s3 * F_MID + f];
    }
    for (; j < cnt; ++j) a0 += g1[(size_t)col[base + j] * F_MID + f];
    float acc = ((a0 + a1) + (a2 + a3)) + ((a4 + a5) + (a6 + a7));
    h[(size_t)d * F_MID + f] = fmaxf(acc * dis[d] + b1[f], 0.0f);
}

// g2[r,j] = (h[r,:] @ W2[:,j]) * dis[r]
// lane = row (64 rows/block), wave w -> features [8w, 8w+8)
__global__ __launch_bounds__(256, 4) void k_gemm2(
    const float* __restrict__ h, const float* __restrict__ W2,
    const float* __restrict__ dis, float* __restrict__ g2, int n) {
    __shared__ float hs[64 * 65];    // pad 65: conflict-free
    int tid  = threadIdx.x;
    int row0 = blockIdx.x * 64;
    for (int i = tid; i < 64 * F_MID; i += 256) {
        int r = i >> 6, k = i & 63;
        int gr = row0 + r;
        hs[r * 65 + k] = (gr < n) ? h[(size_t)gr * F_MID + k] : 0.0f;
    }
    __syncthreads();
    int w = RFL(tid >> 6);
    int r = tid & 63;
    const float4* W4 = (const float4*)W2;   // [64][8] float4 view
    float4 a0 = {0.f,0.f,0.f,0.f}, a1 = a0;
#pragma unroll 4
    for (int k = 0; k < F_MID; ++k) {
        float hv = hs[r * 65 + k];
        float4 w0 = W4[k * 8 + w * 2 + 0];
        float4 w1 = W4[k * 8 + w * 2 + 1];
        a0.x += hv * w0.x; a0.y += hv * w0.y; a0.z += hv * w0.z; a0.w += hv * w0.w;
        a1.x += hv * w1.x; a1.y += hv * w1.y; a1.z += hv * w1.z; a1.w += hv * w1.w;
    }
    int gr = row0 + r;
    if (gr < n) {
        float dv = dis[gr];
        a0.x *= dv; a0.y *= dv; a0.z *= dv; a0.w *= dv;
        a1.x *= dv; a1.y *= dv; a1.z *= dv; a1.w *= dv;
        float4* o4 = (float4*)&g2[(size_t)gr * F_OUT + w * 8];
        o4[0] = a0; o4[1] = a1;
    }
}

// one wave per dst row: lanes = 32 features x 2 neighbor slots; shfl_xor(32) combine
__global__ __launch_bounds__(256) void k_gather2(
    const int* __restrict__ rowstart, const int* __restrict__ deg,
    const int* __restrict__ col, const float* __restrict__ g2,
    const float* __restrict__ dis, const float* __restrict__ b2,
    float* __restrict__ out, int n) {
    int wave = RFL(threadIdx.x >> 6);
    int lane = threadIdx.x & 63;
    int j    = lane & 31;   // feature
    int p    = lane >> 5;   // neighbor slot 0/1
    int d    = blockIdx.x * 4 + wave;
    if (d >= n) return;
    int base = RFL(rowstart[d]);
    int cnt  = RFL(deg[d]);
    float a0 = (p == 0) ? g2[(size_t)d * F_OUT + j] : 0.0f;  // self-loop
    float a1 = 0.f, a2 = 0.f, a3 = 0.f;
    int t = 0;
    for (; t + 8 <= cnt; t += 8) {
        int sA0 = col[base + t + 0], sA1 = col[base + t + 1];
        int sB0 = col[base + t + 2], sB1 = col[base + t + 3];
        int sC0 = col[base + t + 4], sC1 = col[base + t + 5];
        int sD0 = col[base + t + 6], sD1 = col[base + t + 7];
        int sA = p ? sA1 : sA0;
        int sB = p ? sB1 : sB0;
        int sC = p ? sC1 : sC0;
        int sD = p ? sD1 : sD0;
        a0 += g2[(size_t)sA * F_OUT + j];
        a1 += g2[(size_t)sB * F_OUT + j];
        a2 += g2[(size_t)sC * F_OUT + j];
        a3 += g2[(size_t)sD * F_OUT + j];
    }
    for (; t + 2 <= cnt; t += 2) {
        int s0 = col[base + t], s1 = col[base + t + 1];
        int s = p ? s1 : s0;
        a0 += g2[(size_t)s * F_OUT + j];
    }
    if (t < cnt) {  // odd leftover: slot 0 only
        int s = col[base + t];
        if (p == 0) a0 += g2[(size_t)s * F_OUT + j];
    }
    float acc = (a0 + a1) + (a2 + a3);
    acc += __shfl_xor(acc, 32);
    if (p == 0) out[(size_t)d * F_OUT + j] = acc * dis[d] + b2[j];
}

extern "C" void kernel_launch(void* const* d_in, const int* in_sizes, int n_in,
                              void* d_out, int out_size, void* d_ws, size_t ws_size,
                              hipStream_t stream) {
    const float* x  = (const float*)d_in[0];
    const int*   ei = (const int*)d_in[1];
    const float* W1 = (const float*)d_in[2];
    const float* b1 = (const float*)d_in[3];
    const float* W2 = (const float*)d_in[4];
    const float* b2 = (const float*)d_in[5];

    int n = in_sizes[0] / F_IN;   // 50000
    int E = in_sizes[1] / 2;      // 800000
    const int* src = ei;
    const int* dst = ei + E;

    char* ws = (char*)d_ws;
    size_t off = 0;
    auto alloc = [&](size_t bytes) {
        char* p = ws + off;
        off += (bytes + 255) & ~(size_t)255;
        return p;
    };
    int*   deg      = (int*)  alloc((size_t)n * 4);   // in-degree (no self-loop)
    float* dis      = (float*)alloc((size_t)n * 4);
    int*   rowstart = (int*)  alloc((size_t)n * 4);
    int*   cursor   = (int*)  alloc((size_t)n * 4);
    int*   bsum     = (int*)  alloc((size_t)SCAN_B * 4);
    int*   col      = (int*)  alloc((size_t)E * 4);
    float* g1       = (float*)alloc((size_t)n * F_MID * 4);
    float* h        = (float*)alloc((size_t)n * F_MID * 4);
    float* g2       = (float*)alloc((size_t)n * F_OUT * 4);

    int B = 256;
    int nb = (n + SCAN_B - 1) / SCAN_B;  // 196 < SCAN_B (k_scan_bsums requirement)

    hipMemsetAsync(deg, 0, (size_t)n * 4, stream);
    k_deg_edges<<<(E + B - 1) / B, B, 0, stream>>>(dst, E, deg);

    k_scan_partial<<<nb, SCAN_B, 0, stream>>>(deg, n, bsum);
    k_scan_bsums<<<1, SCAN_B, 0, stream>>>(bsum, nb);
    k_scan_final<<<nb, SCAN_B, 0, stream>>>(deg, n, bsum, rowstart, cursor, dis);

    k_fill<<<(E + B - 1) / B, B, 0, stream>>>(src, dst, E, cursor, col);

    k_gemm1<<<(n + 63) / 64, 256, 0, stream>>>(x, W1, dis, g1, n);
    k_gather1<<<(n + 3) / 4, 256, 0, stream>>>(rowstart, deg, col, g1, dis, b1, h, n);
    k_gemm2<<<(n + 63) / 64, 256, 0, stream>>>(h, W2, dis, g2, n);
    k_gather2<<<(n + 3) / 4, 256, 0, stream>>>(rowstart, deg, col, g2, dis, b2,
                                               (float*)d_out, n);
}

// Round 5
// 208.714 us; speedup vs baseline: 1.6171x; 1.2214x over previous
//
#include <hip/hip_runtime.h>

// GCN 2-layer: x[N,128] -> GCNConv(W1[128,64]) -> relu -> GCNConv(W2[64,32])
// out[d] = dis[d] * (g[d] + sum_{e: dst=d} g[src]) + b,  g = (x@W)*dis.
// R4: CSR build via LDS counting sort (bucket = dst>>8), ZERO global atomics.
//     Replaces k_deg_edges + scans + k_fill (all HBM-side atomic RMW bound).

#define F_IN 128
#define F_MID 64
#define F_OUT 32
#define NBLK 256

#define RFL(x) __builtin_amdgcn_readfirstlane(x)

// ---- Pass A: per-block bucket histogram (bucket = dst >> 8) ----
__global__ __launch_bounds__(256) void k_hist(
    const int* __restrict__ dst, int E, int chunk, int nbuk,
    int* __restrict__ blockHist) {
    __shared__ int cnt[256];
    int t = threadIdx.x;
    cnt[t] = 0;
    __syncthreads();
    int e0 = blockIdx.x * chunk;
    int e1 = min(E, e0 + chunk);
    for (int e = e0 + t; e < e1; e += 256)
        atomicAdd(&cnt[dst[e] >> 8], 1);
    __syncthreads();
    if (t < nbuk) blockHist[blockIdx.x * nbuk + t] = cnt[t];
}

// ---- Pass B: one block; bucketStart (excl scan of totals) + blockOff ----
__global__ __launch_bounds__(256) void k_hist_scan(
    const int* __restrict__ blockHist, int nbuk,
    int* __restrict__ blockOff, int* __restrict__ bucketStart) {
    __shared__ int s[256];
    int t = threadIdx.x;
    int total = 0;
    if (t < nbuk)
        for (int blk = 0; blk < NBLK; ++blk) total += blockHist[blk * nbuk + t];
    s[t] = total;
    __syncthreads();
    for (int o = 1; o < 256; o <<= 1) {
        int add = (t >= o) ? s[t - o] : 0;
        __syncthreads();
        s[t] += add;
        __syncthreads();
    }
    int ex = s[t] - total;
    if (t < nbuk) {
        bucketStart[t] = ex;
        if (t == nbuk - 1) bucketStart[nbuk] = s[t];
        int running = ex;
        for (int blk = 0; blk < NBLK; ++blk) {
            blockOff[blk * nbuk + t] = running;
            running += blockHist[blk * nbuk + t];
        }
    }
}

// ---- Pass C: scatter (dst,src) pairs into bucket-ordered esort ----
__global__ __launch_bounds__(256) void k_scatter_edges(
    const int* __restrict__ src, const int* __restrict__ dst, int E, int chunk,
    int nbuk, const int* __restrict__ blockOff, int2* __restrict__ esort) {
    __shared__ int off[256];
    int t = threadIdx.x;
    if (t < nbuk) off[t] = blockOff[blockIdx.x * nbuk + t];
    __syncthreads();
    int e0 = blockIdx.x * chunk;
    int e1 = min(E, e0 + chunk);
    for (int e = e0 + t; e < e1; e += 256) {
        int d = dst[e];
        int pos = atomicAdd(&off[d >> 8], 1);
        esort[pos] = make_int2(d, src[e]);
    }
}

// ---- Pass D: per-bucket exact CSR: deg, rowstart, dis, ordered col ----
__global__ __launch_bounds__(256) void k_bucket_csr(
    const int2* __restrict__ esort, const int* __restrict__ bucketStart, int n,
    int* __restrict__ rowstart, int* __restrict__ deg, float* __restrict__ dis,
    int* __restrict__ col) {
    __shared__ int cnt[256];
    __shared__ int s[256];
    __shared__ int cur[256];
    int b = blockIdx.x;
    int t = threadIdx.x;
    int node0 = b << 8;
    int e0 = bucketStart[b], e1 = bucketStart[b + 1];
    cnt[t] = 0;
    __syncthreads();
    for (int e = e0 + t; e < e1; e += 256)
        atomicAdd(&cnt[esort[e].x & 255], 1);
    __syncthreads();
    int v = cnt[t];
    s[t] = v;
    __syncthreads();
    for (int o = 1; o < 256; o <<= 1) {
        int add = (t >= o) ? s[t - o] : 0;
        __syncthreads();
        s[t] += add;
        __syncthreads();
    }
    int ex = s[t] - v;
    cur[t] = ex;
    int node = node0 + t;
    if (node < n) {
        rowstart[node] = e0 + ex;
        deg[node] = v;                       // in-degree (no self-loop)
        dis[node] = rsqrtf((float)(v + 1));  // +1 self-loop
    }
    __syncthreads();
    for (int e = e0 + t; e < e1; e += 256) {
        int2 p = esort[e];
        int pos = atomicAdd(&cur[p.x & 255], 1);
        col[e0 + pos] = p.y;
    }
}

// g1[r,f] = (x[r,:] @ W1[:,f]) * dis[r]
// lane = row (64 rows/block), wave w -> features [16w, 16w+16)
__global__ __launch_bounds__(256, 4) void k_gemm1(
    const float* __restrict__ x, const float* __restrict__ W1,
    const float* __restrict__ dis, float* __restrict__ g1, int n) {
    __shared__ float xs[64 * 129];   // pad 129: bank (r+k)%32, conflict-free
    int tid  = threadIdx.x;
    int row0 = blockIdx.x * 64;
    for (int i = tid; i < 64 * F_IN; i += 256) {
        int r = i >> 7, k = i & 127;
        int gr = row0 + r;
        xs[r * 129 + k] = (gr < n) ? x[(size_t)gr * F_IN + k] : 0.0f;
    }
    __syncthreads();
    int w = RFL(tid >> 6);   // wave id 0..3 (uniform -> W loads become s_load)
    int r = tid & 63;        // row lane
    const float4* W4 = (const float4*)W1;   // [128][16] float4 view
    float4 a0 = {0.f,0.f,0.f,0.f}, a1 = a0, a2 = a0, a3 = a0;
#pragma unroll 4
    for (int k = 0; k < F_IN; ++k) {
        float xv = xs[r * 129 + k];
        float4 w0 = W4[k * 16 + w * 4 + 0];
        float4 w1 = W4[k * 16 + w * 4 + 1];
        float4 w2 = W4[k * 16 + w * 4 + 2];
        float4 w3 = W4[k * 16 + w * 4 + 3];
        a0.x += xv * w0.x; a0.y += xv * w0.y; a0.z += xv * w0.z; a0.w += xv * w0.w;
        a1.x += xv * w1.x; a1.y += xv * w1.y; a1.z += xv * w1.z; a1.w += xv * w1.w;
        a2.x += xv * w2.x; a2.y += xv * w2.y; a2.z += xv * w2.z; a2.w += xv * w2.w;
        a3.x += xv * w3.x; a3.y += xv * w3.y; a3.z += xv * w3.z; a3.w += xv * w3.w;
    }
    int gr = row0 + r;
    if (gr < n) {
        float dv = dis[gr];
        a0.x *= dv; a0.y *= dv; a0.z *= dv; a0.w *= dv;
        a1.x *= dv; a1.y *= dv; a1.z *= dv; a1.w *= dv;
        a2.x *= dv; a2.y *= dv; a2.z *= dv; a2.w *= dv;
        a3.x *= dv; a3.y *= dv; a3.z *= dv; a3.w *= dv;
        float4* o4 = (float4*)&g1[(size_t)gr * F_MID + w * 16];
        o4[0] = a0; o4[1] = a1; o4[2] = a2; o4[3] = a3;
    }
}

// one wave per dst row; 8 gathers in flight; col via wave-uniform scalar loads
__global__ __launch_bounds__(256) void k_gather1(
    const int* __restrict__ rowstart, const int* __restrict__ deg,
    const int* __restrict__ col, const float* __restrict__ g1,
    const float* __restrict__ dis, const float* __restrict__ b1,
    float* __restrict__ h, int n) {
    int wave = RFL(threadIdx.x >> 6);
    int f    = threadIdx.x & 63;
    int d    = blockIdx.x * 4 + wave;
    if (d >= n) return;
    int base = RFL(rowstart[d]);
    int cnt  = RFL(deg[d]);
    float a0 = g1[(size_t)d * F_MID + f];  // self-loop
    float a1 = 0.f, a2 = 0.f, a3 = 0.f, a4 = 0.f, a5 = 0.f, a6 = 0.f, a7 = 0.f;
    int j = 0;
    for (; j + 8 <= cnt; j += 8) {
        int s0 = col[base + j + 0], s1 = col[base + j + 1];
        int s2 = col[base + j + 2], s3 = col[base + j + 3];
        int s4 = col[base + j + 4], s5 = col[base + j + 5];
        int s6 = col[base + j + 6], s7 = col[base + j + 7];
        a0 += g1[(size_t)s0 * F_MID + f];
        a1 += g1[(size_t)s1 * F_MID + f];
        a2 += g1[(size_t)s2 * F_MID + f];
        a3 += g1[(size_t)s3 * F_MID + f];
        a4 += g1[(size_t)s4 * F_MID + f];
        a5 += g1[(size_t)s5 * F_MID + f];
        a6 += g1[(size_t)s6 * F_MID + f];
        a7 += g1[(size_t)s7 * F_MID + f];
    }
    for (; j + 4 <= cnt; j += 4) {
        int s0 = col[base + j + 0], s1 = col[base + j + 1];
        int s2 = col[base + j + 2], s3 = col[base + j + 3];
        a0 += g1[(size_t)s0 * F_MID + f];
        a1 += g1[(size_t)s1 * F_MID + f];
        a2 += g1[(size_t)s2 * F_MID + f];
        a3 += g1[(size_t)s3 * F_MID + f];
    }
    for (; j < cnt; ++j) a0 += g1[(size_t)col[base + j] * F_MID + f];
    float acc = ((a0 + a1) + (a2 + a3)) + ((a4 + a5) + (a6 + a7));
    h[(size_t)d * F_MID + f] = fmaxf(acc * dis[d] + b1[f], 0.0f);
}

// g2[r,j] = (h[r,:] @ W2[:,j]) * dis[r]
// lane = row (64 rows/block), wave w -> features [8w, 8w+8)
__global__ __launch_bounds__(256, 4) void k_gemm2(
    const float* __restrict__ h, const float* __restrict__ W2,
    const float* __restrict__ dis, float* __restrict__ g2, int n) {
    __shared__ float hs[64 * 65];    // pad 65: conflict-free
    int tid  = threadIdx.x;
    int row0 = blockIdx.x * 64;
    for (int i = tid; i < 64 * F_MID; i += 256) {
        int r = i >> 6, k = i & 63;
        int gr = row0 + r;
        hs[r * 65 + k] = (gr < n) ? h[(size_t)gr * F_MID + k] : 0.0f;
    }
    __syncthreads();
    int w = RFL(tid >> 6);
    int r = tid & 63;
    const float4* W4 = (const float4*)W2;   // [64][8] float4 view
    float4 a0 = {0.f,0.f,0.f,0.f}, a1 = a0;
#pragma unroll 4
    for (int k = 0; k < F_MID; ++k) {
        float hv = hs[r * 65 + k];
        float4 w0 = W4[k * 8 + w * 2 + 0];
        float4 w1 = W4[k * 8 + w * 2 + 1];
        a0.x += hv * w0.x; a0.y += hv * w0.y; a0.z += hv * w0.z; a0.w += hv * w0.w;
        a1.x += hv * w1.x; a1.y += hv * w1.y; a1.z += hv * w1.z; a1.w += hv * w1.w;
    }
    int gr = row0 + r;
    if (gr < n) {
        float dv = dis[gr];
        a0.x *= dv; a0.y *= dv; a0.z *= dv; a0.w *= dv;
        a1.x *= dv; a1.y *= dv; a1.z *= dv; a1.w *= dv;
        float4* o4 = (float4*)&g2[(size_t)gr * F_OUT + w * 8];
        o4[0] = a0; o4[1] = a1;
    }
}

// one wave per dst row: lanes = 32 features x 2 neighbor slots; shfl_xor(32) combine
__global__ __launch_bounds__(256) void k_gather2(
    const int* __restrict__ rowstart, const int* __restrict__ deg,
    const int* __restrict__ col, const float* __restrict__ g2,
    const float* __restrict__ dis, const float* __restrict__ b2,
    float* __restrict__ out, int n) {
    int wave = RFL(threadIdx.x >> 6);
    int lane = threadIdx.x & 63;
    int j    = lane & 31;   // feature
    int p    = lane >> 5;   // neighbor slot 0/1
    int d    = blockIdx.x * 4 + wave;
    if (d >= n) return;
    int base = RFL(rowstart[d]);
    int cnt  = RFL(deg[d]);
    float a0 = (p == 0) ? g2[(size_t)d * F_OUT + j] : 0.0f;  // self-loop
    float a1 = 0.f, a2 = 0.f, a3 = 0.f;
    int t = 0;
    for (; t + 8 <= cnt; t += 8) {
        int sA0 = col[base + t + 0], sA1 = col[base + t + 1];
        int sB0 = col[base + t + 2], sB1 = col[base + t + 3];
        int sC0 = col[base + t + 4], sC1 = col[base + t + 5];
        int sD0 = col[base + t + 6], sD1 = col[base + t + 7];
        int sA = p ? sA1 : sA0;
        int sB = p ? sB1 : sB0;
        int sC = p ? sC1 : sC0;
        int sD = p ? sD1 : sD0;
        a0 += g2[(size_t)sA * F_OUT + j];
        a1 += g2[(size_t)sB * F_OUT + j];
        a2 += g2[(size_t)sC * F_OUT + j];
        a3 += g2[(size_t)sD * F_OUT + j];
    }
    for (; t + 2 <= cnt; t += 2) {
        int s0 = col[base + t], s1 = col[base + t + 1];
        int s = p ? s1 : s0;
        a0 += g2[(size_t)s * F_OUT + j];
    }
    if (t < cnt) {  // odd leftover: slot 0 only
        int s = col[base + t];
        if (p == 0) a0 += g2[(size_t)s * F_OUT + j];
    }
    float acc = (a0 + a1) + (a2 + a3);
    acc += __shfl_xor(acc, 32);
    if (p == 0) out[(size_t)d * F_OUT + j] = acc * dis[d] + b2[j];
}

extern "C" void kernel_launch(void* const* d_in, const int* in_sizes, int n_in,
                              void* d_out, int out_size, void* d_ws, size_t ws_size,
                              hipStream_t stream) {
    const float* x  = (const float*)d_in[0];
    const int*   ei = (const int*)d_in[1];
    const float* W1 = (const float*)d_in[2];
    const float* b1 = (const float*)d_in[3];
    const float* W2 = (const float*)d_in[4];
    const float* b2 = (const float*)d_in[5];

    int n = in_sizes[0] / F_IN;   // 50000
    int E = in_sizes[1] / 2;      // 800000
    const int* src = ei;
    const int* dst = ei + E;

    int nbuk  = (n + 255) >> 8;   // 196 (must be <= 256)
    int chunk = (E + NBLK - 1) / NBLK;

    char* ws = (char*)d_ws;
    size_t off = 0;
    auto alloc = [&](size_t bytes) {
        char* p = ws + off;
        off += (bytes + 255) & ~(size_t)255;
        return p;
    };
    int*   blockHist   = (int*)  alloc((size_t)NBLK * nbuk * 4);
    int*   blockOff    = (int*)  alloc((size_t)NBLK * nbuk * 4);
    int*   bucketStart = (int*)  alloc((size_t)(nbuk + 1) * 4);
    int2*  esort       = (int2*) alloc((size_t)E * 8);
    int*   col         = (int*)  alloc((size_t)E * 4);
    int*   rowstart    = (int*)  alloc((size_t)n * 4);
    int*   deg         = (int*)  alloc((size_t)n * 4);
    float* dis         = (float*)alloc((size_t)n * 4);
    float* g1          = (float*)alloc((size_t)n * F_MID * 4);
    float* h           = (float*)alloc((size_t)n * F_MID * 4);
    float* g2          = (float*)alloc((size_t)n * F_OUT * 4);

    k_hist<<<NBLK, 256, 0, stream>>>(dst, E, chunk, nbuk, blockHist);
    k_hist_scan<<<1, 256, 0, stream>>>(blockHist, nbuk, blockOff, bucketStart);
    k_scatter_edges<<<NBLK, 256, 0, stream>>>(src, dst, E, chunk, nbuk, blockOff, esort);
    k_bucket_csr<<<nbuk, 256, 0, stream>>>(esort, bucketStart, n, rowstart, deg, dis, col);

    k_gemm1<<<(n + 63) / 64, 256, 0, stream>>>(x, W1, dis, g1, n);
    k_gather1<<<(n + 3) / 4, 256, 0, stream>>>(rowstart, deg, col, g1, dis, b1, h, n);
    k_gemm2<<<(n + 63) / 64, 256, 0, stream>>>(h, W2, dis, g2, n);
    k_gather2<<<(n + 3) / 4, 256, 0, stream>>>(rowstart, deg, col, g2, dis, b2,
                                               (float*)d_out, n);
}

// Round 6
// 198.879 us; speedup vs baseline: 1.6971x; 1.0495x over previous
//
#include <hip/hip_runtime.h>

// GCN 2-layer: x[N,128] -> GCNConv(W1[128,64]) -> relu -> GCNConv(W2[64,32])
// out[d] = dis[d] * (g[d] + sum_{e: dst=d} g[src]) + b,  g = (x@W)*dis.
// R5: parallelized the histogram scan (R4's k_hist_scan was a single-block
//     serial 256-iter dependent-load chain, ~30us). Build is now:
//     hist -> scan_buckets(196 blocks) -> scan_starts(1 tiny) -> scatter -> csr.

#define F_IN 128
#define F_MID 64
#define F_OUT 32
#define NBLK 256

#define RFL(x) __builtin_amdgcn_readfirstlane(x)

// ---- Pass A: per-block bucket histogram (bucket = dst >> 8) ----
__global__ __launch_bounds__(256) void k_hist(
    const int* __restrict__ dst, int E, int chunk, int nbuk,
    int* __restrict__ blockHist) {
    __shared__ int cnt[256];
    int t = threadIdx.x;
    cnt[t] = 0;
    __syncthreads();
    int e0 = blockIdx.x * chunk;
    int e1 = min(E, e0 + chunk);
    for (int e = e0 + t; e < e1; e += 256)
        atomicAdd(&cnt[dst[e] >> 8], 1);
    __syncthreads();
    if (t < nbuk) blockHist[blockIdx.x * nbuk + t] = cnt[t];
}

// ---- Pass B1: one block per bucket; parallel scan over the NBLK blocks ----
__global__ __launch_bounds__(NBLK) void k_scan_buckets(
    const int* __restrict__ blockHist, int nbuk,
    int* __restrict__ blockOff, int* __restrict__ bucketTotal) {
    __shared__ int s[NBLK];
    int b = blockIdx.x;
    int t = threadIdx.x;
    int v = blockHist[t * nbuk + b];
    s[t] = v;
    __syncthreads();
    for (int o = 1; o < NBLK; o <<= 1) {
        int add = (t >= o) ? s[t - o] : 0;
        __syncthreads();
        s[t] += add;
        __syncthreads();
    }
    blockOff[t * nbuk + b] = s[t] - v;      // exclusive within bucket
    if (t == NBLK - 1) bucketTotal[b] = s[t];
}

// ---- Pass B2: one tiny block; exclusive scan of bucket totals ----
__global__ __launch_bounds__(256) void k_scan_starts(
    const int* __restrict__ bucketTotal, int nbuk, int E,
    int* __restrict__ bucketStart) {
    __shared__ int s[256];
    int t = threadIdx.x;
    int v = (t < nbuk) ? bucketTotal[t] : 0;
    s[t] = v;
    __syncthreads();
    for (int o = 1; o < 256; o <<= 1) {
        int add = (t >= o) ? s[t - o] : 0;
        __syncthreads();
        s[t] += add;
        __syncthreads();
    }
    if (t < nbuk) bucketStart[t] = s[t] - v;
    if (t == 0) bucketStart[nbuk] = E;
}

// ---- Pass C: scatter (dst,src) pairs into bucket-ordered esort ----
__global__ __launch_bounds__(256) void k_scatter_edges(
    const int* __restrict__ src, const int* __restrict__ dst, int E, int chunk,
    int nbuk, const int* __restrict__ blockOff, const int* __restrict__ bucketStart,
    int2* __restrict__ esort) {
    __shared__ int off[256];
    int t = threadIdx.x;
    if (t < nbuk) off[t] = blockOff[blockIdx.x * nbuk + t] + bucketStart[t];
    __syncthreads();
    int e0 = blockIdx.x * chunk;
    int e1 = min(E, e0 + chunk);
    for (int e = e0 + t; e < e1; e += 256) {
        int d = dst[e];
        int pos = atomicAdd(&off[d >> 8], 1);
        esort[pos] = make_int2(d, src[e]);
    }
}

// ---- Pass D: per-bucket exact CSR: deg, rowstart, dis, ordered col ----
__global__ __launch_bounds__(256) void k_bucket_csr(
    const int2* __restrict__ esort, const int* __restrict__ bucketStart, int n,
    int* __restrict__ rowstart, int* __restrict__ deg, float* __restrict__ dis,
    int* __restrict__ col) {
    __shared__ int cnt[256];
    __shared__ int s[256];
    __shared__ int cur[256];
    int b = blockIdx.x;
    int t = threadIdx.x;
    int node0 = b << 8;
    int e0 = bucketStart[b], e1 = bucketStart[b + 1];
    cnt[t] = 0;
    __syncthreads();
    for (int e = e0 + t; e < e1; e += 256)
        atomicAdd(&cnt[esort[e].x & 255], 1);
    __syncthreads();
    int v = cnt[t];
    s[t] = v;
    __syncthreads();
    for (int o = 1; o < 256; o <<= 1) {
        int add = (t >= o) ? s[t - o] : 0;
        __syncthreads();
        s[t] += add;
        __syncthreads();
    }
    int ex = s[t] - v;
    cur[t] = ex;
    int node = node0 + t;
    if (node < n) {
        rowstart[node] = e0 + ex;
        deg[node] = v;                       // in-degree (no self-loop)
        dis[node] = rsqrtf((float)(v + 1));  // +1 self-loop
    }
    __syncthreads();
    for (int e = e0 + t; e < e1; e += 256) {
        int2 p = esort[e];
        int pos = atomicAdd(&cur[p.x & 255], 1);
        col[e0 + pos] = p.y;
    }
}

// g1[r,f] = (x[r,:] @ W1[:,f]) * dis[r]
// lane = row (64 rows/block), wave w -> features [16w, 16w+16)
__global__ __launch_bounds__(256, 4) void k_gemm1(
    const float* __restrict__ x, const float* __restrict__ W1,
    const float* __restrict__ dis, float* __restrict__ g1, int n) {
    __shared__ float xs[64 * 129];   // pad 129: bank (r+k)%32, conflict-free
    int tid  = threadIdx.x;
    int row0 = blockIdx.x * 64;
    for (int i = tid; i < 64 * F_IN; i += 256) {
        int r = i >> 7, k = i & 127;
        int gr = row0 + r;
        xs[r * 129 + k] = (gr < n) ? x[(size_t)gr * F_IN + k] : 0.0f;
    }
    __syncthreads();
    int w = RFL(tid >> 6);   // wave id 0..3 (uniform -> W loads become s_load)
    int r = tid & 63;        // row lane
    const float4* W4 = (const float4*)W1;   // [128][16] float4 view
    float4 a0 = {0.f,0.f,0.f,0.f}, a1 = a0, a2 = a0, a3 = a0;
#pragma unroll 4
    for (int k = 0; k < F_IN; ++k) {
        float xv = xs[r * 129 + k];
        float4 w0 = W4[k * 16 + w * 4 + 0];
        float4 w1 = W4[k * 16 + w * 4 + 1];
        float4 w2 = W4[k * 16 + w * 4 + 2];
        float4 w3 = W4[k * 16 + w * 4 + 3];
        a0.x += xv * w0.x; a0.y += xv * w0.y; a0.z += xv * w0.z; a0.w += xv * w0.w;
        a1.x += xv * w1.x; a1.y += xv * w1.y; a1.z += xv * w1.z; a1.w += xv * w1.w;
        a2.x += xv * w2.x; a2.y += xv * w2.y; a2.z += xv * w2.z; a2.w += xv * w2.w;
        a3.x += xv * w3.x; a3.y += xv * w3.y; a3.z += xv * w3.z; a3.w += xv * w3.w;
    }
    int gr = row0 + r;
    if (gr < n) {
        float dv = dis[gr];
        a0.x *= dv; a0.y *= dv; a0.z *= dv; a0.w *= dv;
        a1.x *= dv; a1.y *= dv; a1.z *= dv; a1.w *= dv;
        a2.x *= dv; a2.y *= dv; a2.z *= dv; a2.w *= dv;
        a3.x *= dv; a3.y *= dv; a3.z *= dv; a3.w *= dv;
        float4* o4 = (float4*)&g1[(size_t)gr * F_MID + w * 16];
        o4[0] = a0; o4[1] = a1; o4[2] = a2; o4[3] = a3;
    }
}

// one wave per dst row; 8 gathers in flight; col via wave-uniform scalar loads
__global__ __launch_bounds__(256) void k_gather1(
    const int* __restrict__ rowstart, const int* __restrict__ deg,
    const int* __restrict__ col, const float* __restrict__ g1,
    const float* __restrict__ dis, const float* __restrict__ b1,
    float* __restrict__ h, int n) {
    int wave = RFL(threadIdx.x >> 6);
    int f    = threadIdx.x & 63;
    int d    = blockIdx.x * 4 + wave;
    if (d >= n) return;
    int base = RFL(rowstart[d]);
    int cnt  = RFL(deg[d]);
    float a0 = g1[(size_t)d * F_MID + f];  // self-loop
    float a1 = 0.f, a2 = 0.f, a3 = 0.f, a4 = 0.f, a5 = 0.f, a6 = 0.f, a7 = 0.f;
    int j = 0;
    for (; j + 8 <= cnt; j += 8) {
        int s0 = col[base + j + 0], s1 = col[base + j + 1];
        int s2 = col[base + j + 2], s3 = col[base + j + 3];
        int s4 = col[base + j + 4], s5 = col[base + j + 5];
        int s6 = col[base + j + 6], s7 = col[base + j + 7];
        a0 += g1[(size_t)s0 * F_MID + f];
        a1 += g1[(size_t)s1 * F_MID + f];
        a2 += g1[(size_t)s2 * F_MID + f];
        a3 += g1[(size_t)s3 * F_MID + f];
        a4 += g1[(size_t)s4 * F_MID + f];
        a5 += g1[(size_t)s5 * F_MID + f];
        a6 += g1[(size_t)s6 * F_MID + f];
        a7 += g1[(size_t)s7 * F_MID + f];
    }
    for (; j + 4 <= cnt; j += 4) {
        int s0 = col[base + j + 0], s1 = col[base + j + 1];
        int s2 = col[base + j + 2], s3 = col[base + j + 3];
        a0 += g1[(size_t)s0 * F_MID + f];
        a1 += g1[(size_t)s1 * F_MID + f];
        a2 += g1[(size_t)s2 * F_MID + f];
        a3 += g1[(size_t)s3 * F_MID + f];
    }
    for (; j < cnt; ++j) a0 += g1[(size_t)col[base + j] * F_MID + f];
    float acc = ((a0 + a1) + (a2 + a3)) + ((a4 + a5) + (a6 + a7));
    h[(size_t)d * F_MID + f] = fmaxf(acc * dis[d] + b1[f], 0.0f);
}

// g2[r,j] = (h[r,:] @ W2[:,j]) * dis[r]
// lane = row (64 rows/block), wave w -> features [8w, 8w+8)
__global__ __launch_bounds__(256, 4) void k_gemm2(
    const float* __restrict__ h, const float* __restrict__ W2,
    const float* __restrict__ dis, float* __restrict__ g2, int n) {
    __shared__ float hs[64 * 65];    // pad 65: conflict-free
    int tid  = threadIdx.x;
    int row0 = blockIdx.x * 64;
    for (int i = tid; i < 64 * F_MID; i += 256) {
        int r = i >> 6, k = i & 63;
        int gr = row0 + r;
        hs[r * 65 + k] = (gr < n) ? h[(size_t)gr * F_MID + k] : 0.0f;
    }
    __syncthreads();
    int w = RFL(tid >> 6);
    int r = tid & 63;
    const float4* W4 = (const float4*)W2;   // [64][8] float4 view
    float4 a0 = {0.f,0.f,0.f,0.f}, a1 = a0;
#pragma unroll 4
    for (int k = 0; k < F_MID; ++k) {
        float hv = hs[r * 65 + k];
        float4 w0 = W4[k * 8 + w * 2 + 0];
        float4 w1 = W4[k * 8 + w * 2 + 1];
        a0.x += hv * w0.x; a0.y += hv * w0.y; a0.z += hv * w0.z; a0.w += hv * w0.w;
        a1.x += hv * w1.x; a1.y += hv * w1.y; a1.z += hv * w1.z; a1.w += hv * w1.w;
    }
    int gr = row0 + r;
    if (gr < n) {
        float dv = dis[gr];
        a0.x *= dv; a0.y *= dv; a0.z *= dv; a0.w *= dv;
        a1.x *= dv; a1.y *= dv; a1.z *= dv; a1.w *= dv;
        float4* o4 = (float4*)&g2[(size_t)gr * F_OUT + w * 8];
        o4[0] = a0; o4[1] = a1;
    }
}

// one wave per dst row: lanes = 32 features x 2 neighbor slots; shfl_xor(32) combine
__global__ __launch_bounds__(256) void k_gather2(
    const int* __restrict__ rowstart, const int* __restrict__ deg,
    const int* __restrict__ col, const float* __restrict__ g2,
    const float* __restrict__ dis, const float* __restrict__ b2,
    float* __restrict__ out, int n) {
    int wave = RFL(threadIdx.x >> 6);
    int lane = threadIdx.x & 63;
    int j    = lane & 31;   // feature
    int p    = lane >> 5;   // neighbor slot 0/1
    int d    = blockIdx.x * 4 + wave;
    if (d >= n) return;
    int base = RFL(rowstart[d]);
    int cnt  = RFL(deg[d]);
    float a0 = (p == 0) ? g2[(size_t)d * F_OUT + j] : 0.0f;  // self-loop
    float a1 = 0.f, a2 = 0.f, a3 = 0.f;
    int t = 0;
    for (; t + 8 <= cnt; t += 8) {
        int sA0 = col[base + t + 0], sA1 = col[base + t + 1];
        int sB0 = col[base + t + 2], sB1 = col[base + t + 3];
        int sC0 = col[base + t + 4], sC1 = col[base + t + 5];
        int sD0 = col[base + t + 6], sD1 = col[base + t + 7];
        int sA = p ? sA1 : sA0;
        int sB = p ? sB1 : sB0;
        int sC = p ? sC1 : sC0;
        int sD = p ? sD1 : sD0;
        a0 += g2[(size_t)sA * F_OUT + j];
        a1 += g2[(size_t)sB * F_OUT + j];
        a2 += g2[(size_t)sC * F_OUT + j];
        a3 += g2[(size_t)sD * F_OUT + j];
    }
    for (; t + 2 <= cnt; t += 2) {
        int s0 = col[base + t], s1 = col[base + t + 1];
        int s = p ? s1 : s0;
        a0 += g2[(size_t)s * F_OUT + j];
    }
    if (t < cnt) {  // odd leftover: slot 0 only
        int s = col[base + t];
        if (p == 0) a0 += g2[(size_t)s * F_OUT + j];
    }
    float acc = (a0 + a1) + (a2 + a3);
    acc += __shfl_xor(acc, 32);
    if (p == 0) out[(size_t)d * F_OUT + j] = acc * dis[d] + b2[j];
}

extern "C" void kernel_launch(void* const* d_in, const int* in_sizes, int n_in,
                              void* d_out, int out_size, void* d_ws, size_t ws_size,
                              hipStream_t stream) {
    const float* x  = (const float*)d_in[0];
    const int*   ei = (const int*)d_in[1];
    const float* W1 = (const float*)d_in[2];
    const float* b1 = (const float*)d_in[3];
    const float* W2 = (const float*)d_in[4];
    const float* b2 = (const float*)d_in[5];

    int n = in_sizes[0] / F_IN;   // 50000
    int E = in_sizes[1] / 2;      // 800000
    const int* src = ei;
    const int* dst = ei + E;

    int nbuk  = (n + 255) >> 8;   // 196 (must be <= 256)
    int chunk = (E + NBLK - 1) / NBLK;

    char* ws = (char*)d_ws;
    size_t off = 0;
    auto alloc = [&](size_t bytes) {
        char* p = ws + off;
        off += (bytes + 255) & ~(size_t)255;
        return p;
    };
    int*   blockHist   = (int*)  alloc((size_t)NBLK * nbuk * 4);
    int*   blockOff    = (int*)  alloc((size_t)NBLK * nbuk * 4);
    int*   bucketTotal = (int*)  alloc((size_t)nbuk * 4);
    int*   bucketStart = (int*)  alloc((size_t)(nbuk + 1) * 4);
    int2*  esort       = (int2*) alloc((size_t)E * 8);
    int*   col         = (int*)  alloc((size_t)E * 4);
    int*   rowstart    = (int*)  alloc((size_t)n * 4);
    int*   deg         = (int*)  alloc((size_t)n * 4);
    float* dis         = (float*)alloc((size_t)n * 4);
    float* g1          = (float*)alloc((size_t)n * F_MID * 4);
    float* h           = (float*)alloc((size_t)n * F_MID * 4);
    float* g2          = (float*)alloc((size_t)n * F_OUT * 4);

    k_hist<<<NBLK, 256, 0, stream>>>(dst, E, chunk, nbuk, blockHist);
    k_scan_buckets<<<nbuk, NBLK, 0, stream>>>(blockHist, nbuk, blockOff, bucketTotal);
    k_scan_starts<<<1, 256, 0, stream>>>(bucketTotal, nbuk, E, bucketStart);
    k_scatter_edges<<<NBLK, 256, 0, stream>>>(src, dst, E, chunk, nbuk, blockOff,
                                              bucketStart, esort);
    k_bucket_csr<<<nbuk, 256, 0, stream>>>(esort, bucketStart, n, rowstart, deg, dis, col);

    k_gemm1<<<(n + 63) / 64, 256, 0, stream>>>(x, W1, dis, g1, n);
    k_gather1<<<(n + 3) / 4, 256, 0, stream>>>(rowstart, deg, col, g1, dis, b1, h, n);
    k_gemm2<<<(n + 63) / 64, 256, 0, stream>>>(h, W2, dis, g2, n);
    k_gather2<<<(n + 3) / 4, 256, 0, stream>>>(rowstart, deg, col, g2, dis, b2,
                                               (float*)d_out, n);
}

// Round 7
// 196.655 us; speedup vs baseline: 1.7163x; 1.0113x over previous
//
#include <hip/hip_runtime.h>

// GCN 2-layer: x[N,128] -> GCNConv(W1[128,64]) -> relu -> GCNConv(W2[64,32])
// out[d] = dis[d] * (g[d] + sum_{e: dst=d} g[src]) + b,  g = (x@W)*dis.
// R6: float4 multi-row gathers (4 rows/VMEM-instr in gather1, 8 in gather2,
//     cross-slot shfl_xor reduce), packed esort (src<<8|d&255).

#define F_IN 128
#define F_MID 64
#define F_OUT 32
#define NBLK 256

#define RFL(x) __builtin_amdgcn_readfirstlane(x)

__device__ __forceinline__ void f4add(float4& a, const float4& b) {
    a.x += b.x; a.y += b.y; a.z += b.z; a.w += b.w;
}

// ---- Pass A: per-block bucket histogram (bucket = dst >> 8) ----
__global__ __launch_bounds__(256) void k_hist(
    const int* __restrict__ dst, int E, int chunk, int nbuk,
    int* __restrict__ blockHist) {
    __shared__ int cnt[256];
    int t = threadIdx.x;
    cnt[t] = 0;
    __syncthreads();
    int e0 = blockIdx.x * chunk;
    int e1 = min(E, e0 + chunk);
    for (int e = e0 + t; e < e1; e += 256)
        atomicAdd(&cnt[dst[e] >> 8], 1);
    __syncthreads();
    if (t < nbuk) blockHist[blockIdx.x * nbuk + t] = cnt[t];
}

// ---- Pass B1: one block per bucket; parallel scan over the NBLK blocks ----
__global__ __launch_bounds__(NBLK) void k_scan_buckets(
    const int* __restrict__ blockHist, int nbuk,
    int* __restrict__ blockOff, int* __restrict__ bucketTotal) {
    __shared__ int s[NBLK];
    int b = blockIdx.x;
    int t = threadIdx.x;
    int v = blockHist[t * nbuk + b];
    s[t] = v;
    __syncthreads();
    for (int o = 1; o < NBLK; o <<= 1) {
        int add = (t >= o) ? s[t - o] : 0;
        __syncthreads();
        s[t] += add;
        __syncthreads();
    }
    blockOff[t * nbuk + b] = s[t] - v;      // exclusive within bucket
    if (t == NBLK - 1) bucketTotal[b] = s[t];
}

// ---- Pass B2: one tiny block; exclusive scan of bucket totals ----
__global__ __launch_bounds__(256) void k_scan_starts(
    const int* __restrict__ bucketTotal, int nbuk, int E,
    int* __restrict__ bucketStart) {
    __shared__ int s[256];
    int t = threadIdx.x;
    int v = (t < nbuk) ? bucketTotal[t] : 0;
    s[t] = v;
    __syncthreads();
    for (int o = 1; o < 256; o <<= 1) {
        int add = (t >= o) ? s[t - o] : 0;
        __syncthreads();
        s[t] += add;
        __syncthreads();
    }
    if (t < nbuk) bucketStart[t] = s[t] - v;
    if (t == 0) bucketStart[nbuk] = E;
}

// ---- Pass C: scatter packed (src<<8 | d&255) into bucket-ordered esort ----
__global__ __launch_bounds__(256) void k_scatter_edges(
    const int* __restrict__ src, const int* __restrict__ dst, int E, int chunk,
    int nbuk, const int* __restrict__ blockOff, const int* __restrict__ bucketStart,
    int* __restrict__ esort) {
    __shared__ int off[256];
    int t = threadIdx.x;
    if (t < nbuk) off[t] = blockOff[blockIdx.x * nbuk + t] + bucketStart[t];
    __syncthreads();
    int e0 = blockIdx.x * chunk;
    int e1 = min(E, e0 + chunk);
    for (int e = e0 + t; e < e1; e += 256) {
        int d = dst[e];
        int pos = atomicAdd(&off[d >> 8], 1);
        esort[pos] = (src[e] << 8) | (d & 255);   // src < 2^24
    }
}

// ---- Pass D: per-bucket exact CSR: deg, rowstart, dis, ordered col ----
__global__ __launch_bounds__(256) void k_bucket_csr(
    const int* __restrict__ esort, const int* __restrict__ bucketStart, int n,
    int* __restrict__ rowstart, int* __restrict__ deg, float* __restrict__ dis,
    int* __restrict__ col) {
    __shared__ int cnt[256];
    __shared__ int s[256];
    __shared__ int cur[256];
    int b = blockIdx.x;
    int t = threadIdx.x;
    int node0 = b << 8;
    int e0 = bucketStart[b], e1 = bucketStart[b + 1];
    cnt[t] = 0;
    __syncthreads();
    for (int e = e0 + t; e < e1; e += 256)
        atomicAdd(&cnt[esort[e] & 255], 1);
    __syncthreads();
    int v = cnt[t];
    s[t] = v;
    __syncthreads();
    for (int o = 1; o < 256; o <<= 1) {
        int add = (t >= o) ? s[t - o] : 0;
        __syncthreads();
        s[t] += add;
        __syncthreads();
    }
    int ex = s[t] - v;
    cur[t] = ex;
    int node = node0 + t;
    if (node < n) {
        rowstart[node] = e0 + ex;
        deg[node] = v;                       // in-degree (no self-loop)
        dis[node] = rsqrtf((float)(v + 1));  // +1 self-loop
    }
    __syncthreads();
    for (int e = e0 + t; e < e1; e += 256) {
        int p = esort[e];
        int pos = atomicAdd(&cur[p & 255], 1);
        col[e0 + pos] = p >> 8;              // src (non-negative)
    }
}

// g1[r,f] = (x[r,:] @ W1[:,f]) * dis[r]
// lane = row (64 rows/block), wave w -> features [16w, 16w+16)
__global__ __launch_bounds__(256, 4) void k_gemm1(
    const float* __restrict__ x, const float* __restrict__ W1,
    const float* __restrict__ dis, float* __restrict__ g1, int n) {
    __shared__ float xs[64 * 129];   // pad 129: bank (r+k)%32, conflict-free
    int tid  = threadIdx.x;
    int row0 = blockIdx.x * 64;
    for (int i = tid; i < 64 * F_IN; i += 256) {
        int r = i >> 7, k = i & 127;
        int gr = row0 + r;
        xs[r * 129 + k] = (gr < n) ? x[(size_t)gr * F_IN + k] : 0.0f;
    }
    __syncthreads();
    int w = RFL(tid >> 6);   // wave id 0..3 (uniform -> W loads become s_load)
    int r = tid & 63;        // row lane
    const float4* W4 = (const float4*)W1;   // [128][16] float4 view
    float4 a0 = {0.f,0.f,0.f,0.f}, a1 = a0, a2 = a0, a3 = a0;
#pragma unroll 4
    for (int k = 0; k < F_IN; ++k) {
        float xv = xs[r * 129 + k];
        float4 w0 = W4[k * 16 + w * 4 + 0];
        float4 w1 = W4[k * 16 + w * 4 + 1];
        float4 w2 = W4[k * 16 + w * 4 + 2];
        float4 w3 = W4[k * 16 + w * 4 + 3];
        a0.x += xv * w0.x; a0.y += xv * w0.y; a0.z += xv * w0.z; a0.w += xv * w0.w;
        a1.x += xv * w1.x; a1.y += xv * w1.y; a1.z += xv * w1.z; a1.w += xv * w1.w;
        a2.x += xv * w2.x; a2.y += xv * w2.y; a2.z += xv * w2.z; a2.w += xv * w2.w;
        a3.x += xv * w3.x; a3.y += xv * w3.y; a3.z += xv * w3.z; a3.w += xv * w3.w;
    }
    int gr = row0 + r;
    if (gr < n) {
        float dv = dis[gr];
        a0.x *= dv; a0.y *= dv; a0.z *= dv; a0.w *= dv;
        a1.x *= dv; a1.y *= dv; a1.z *= dv; a1.w *= dv;
        a2.x *= dv; a2.y *= dv; a2.z *= dv; a2.w *= dv;
        a3.x *= dv; a3.y *= dv; a3.z *= dv; a3.w *= dv;
        float4* o4 = (float4*)&g1[(size_t)gr * F_MID + w * 16];
        o4[0] = a0; o4[1] = a1; o4[2] = a2; o4[3] = a3;
    }
}

// one wave per dst row. lane = (slot 0..3) * 16 + (quarter 0..15).
// One global_load_dwordx4 fetches 4 neighbor rows (1 KB). x4 unroll = 16 rows
// in flight. Cross-slot shfl_xor(16,32) reduce; lanes 0..15 write float4.
__global__ __launch_bounds__(256) void k_gather1(
    const int* __restrict__ rowstart, const int* __restrict__ deg,
    const int* __restrict__ col, const float* __restrict__ g1,
    const float* __restrict__ dis, const float* __restrict__ b1,
    float* __restrict__ h, int n) {
    int wave = RFL(threadIdx.x >> 6);
    int lane = threadIdx.x & 63;
    int q    = lane & 15;   // quarter-row: features 4q..4q+3
    int slot = lane >> 4;   // 0..3
    int d    = blockIdx.x * 4 + wave;
    if (d >= n) return;
    int base = RFL(rowstart[d]);
    int cnt  = RFL(deg[d]);
    const float4* G4 = (const float4*)g1;   // [N][16]
    float4 z = {0.f, 0.f, 0.f, 0.f};
    float4 a0 = (slot == 0) ? G4[(size_t)d * 16 + q] : z;  // self-loop
    float4 a1 = z, a2 = z, a3 = z;
    int j = 0;
    for (; j + 16 <= cnt; j += 16) {
        int s0 = col[base + j + 0  + slot];
        int s1 = col[base + j + 4  + slot];
        int s2 = col[base + j + 8  + slot];
        int s3 = col[base + j + 12 + slot];
        float4 v0 = G4[(size_t)s0 * 16 + q];
        float4 v1 = G4[(size_t)s1 * 16 + q];
        float4 v2 = G4[(size_t)s2 * 16 + q];
        float4 v3 = G4[(size_t)s3 * 16 + q];
        f4add(a0, v0); f4add(a1, v1); f4add(a2, v2); f4add(a3, v3);
    }
    for (; j + 4 <= cnt; j += 4) {
        int s = col[base + j + slot];
        float4 v = G4[(size_t)s * 16 + q];
        f4add(a0, v);
    }
    if (slot < cnt - j) {
        int s = col[base + j + slot];
        float4 v = G4[(size_t)s * 16 + q];
        f4add(a0, v);
    }
    f4add(a0, a1); f4add(a2, a3); f4add(a0, a2);
    a0.x += __shfl_xor(a0.x, 16); a0.y += __shfl_xor(a0.y, 16);
    a0.z += __shfl_xor(a0.z, 16); a0.w += __shfl_xor(a0.w, 16);
    a0.x += __shfl_xor(a0.x, 32); a0.y += __shfl_xor(a0.y, 32);
    a0.z += __shfl_xor(a0.z, 32); a0.w += __shfl_xor(a0.w, 32);
    if (slot == 0) {
        float dv = dis[d];
        float4 bv = ((const float4*)b1)[q];
        float4 o;
        o.x = fmaxf(a0.x * dv + bv.x, 0.f);
        o.y = fmaxf(a0.y * dv + bv.y, 0.f);
        o.z = fmaxf(a0.z * dv + bv.z, 0.f);
        o.w = fmaxf(a0.w * dv + bv.w, 0.f);
        ((float4*)h)[(size_t)d * 16 + q] = o;
    }
}

// g2[r,j] = (h[r,:] @ W2[:,j]) * dis[r]
// lane = row (64 rows/block), wave w -> features [8w, 8w+8)
__global__ __launch_bounds__(256, 4) void k_gemm2(
    const float* __restrict__ h, const float* __restrict__ W2,
    const float* __restrict__ dis, float* __restrict__ g2, int n) {
    __shared__ float hs[64 * 65];    // pad 65: conflict-free
    int tid  = threadIdx.x;
    int row0 = blockIdx.x * 64;
    for (int i = tid; i < 64 * F_MID; i += 256) {
        int r = i >> 6, k = i & 63;
        int gr = row0 + r;
        hs[r * 65 + k] = (gr < n) ? h[(size_t)gr * F_MID + k] : 0.0f;
    }
    __syncthreads();
    int w = RFL(tid >> 6);
    int r = tid & 63;
    const float4* W4 = (const float4*)W2;   // [64][8] float4 view
    float4 a0 = {0.f,0.f,0.f,0.f}, a1 = a0;
#pragma unroll 4
    for (int k = 0; k < F_MID; ++k) {
        float hv = hs[r * 65 + k];
        float4 w0 = W4[k * 8 + w * 2 + 0];
        float4 w1 = W4[k * 8 + w * 2 + 1];
        a0.x += hv * w0.x; a0.y += hv * w0.y; a0.z += hv * w0.z; a0.w += hv * w0.w;
        a1.x += hv * w1.x; a1.y += hv * w1.y; a1.z += hv * w1.z; a1.w += hv * w1.w;
    }
    int gr = row0 + r;
    if (gr < n) {
        float dv = dis[gr];
        a0.x *= dv; a0.y *= dv; a0.z *= dv; a0.w *= dv;
        a1.x *= dv; a1.y *= dv; a1.z *= dv; a1.w *= dv;
        float4* o4 = (float4*)&g2[(size_t)gr * F_OUT + w * 8];
        o4[0] = a0; o4[1] = a1;
    }
}

// one wave per dst row. lane = (slot 0..7) * 8 + (q 0..7). One dwordx4 load
// fetches 8 neighbor rows (128 B each). shfl_xor(8,16,32) reduce; lanes 0..7
// write the float4 output row.
__global__ __launch_bounds__(256) void k_gather2(
    const int* __restrict__ rowstart, const int* __restrict__ deg,
    const int* __restrict__ col, const float* __restrict__ g2,
    const float* __restrict__ dis, const float* __restrict__ b2,
    float* __restrict__ out, int n) {
    int wave = RFL(threadIdx.x >> 6);
    int lane = threadIdx.x & 63;
    int q    = lane & 7;    // features 4q..4q+3
    int slot = lane >> 3;   // 0..7
    int d    = blockIdx.x * 4 + wave;
    if (d >= n) return;
    int base = RFL(rowstart[d]);
    int cnt  = RFL(deg[d]);
    const float4* G4 = (const float4*)g2;   // [N][8]
    float4 z = {0.f, 0.f, 0.f, 0.f};
    float4 a0 = (slot == 0) ? G4[(size_t)d * 8 + q] : z;  // self-loop
    float4 a1 = z;
    int j = 0;
    for (; j + 16 <= cnt; j += 16) {
        int s0 = col[base + j + slot];
        int s1 = col[base + j + 8 + slot];
        float4 v0 = G4[(size_t)s0 * 8 + q];
        float4 v1 = G4[(size_t)s1 * 8 + q];
        f4add(a0, v0); f4add(a1, v1);
    }
    for (; j + 8 <= cnt; j += 8) {
        int s = col[base + j + slot];
        float4 v = G4[(size_t)s * 8 + q];
        f4add(a0, v);
    }
    if (slot < cnt - j) {
        int s = col[base + j + slot];
        float4 v = G4[(size_t)s * 8 + q];
        f4add(a0, v);
    }
    f4add(a0, a1);
    a0.x += __shfl_xor(a0.x, 8);  a0.y += __shfl_xor(a0.y, 8);
    a0.z += __shfl_xor(a0.z, 8);  a0.w += __shfl_xor(a0.w, 8);
    a0.x += __shfl_xor(a0.x, 16); a0.y += __shfl_xor(a0.y, 16);
    a0.z += __shfl_xor(a0.z, 16); a0.w += __shfl_xor(a0.w, 16);
    a0.x += __shfl_xor(a0.x, 32); a0.y += __shfl_xor(a0.y, 32);
    a0.z += __shfl_xor(a0.z, 32); a0.w += __shfl_xor(a0.w, 32);
    if (slot == 0) {
        float dv = dis[d];
        float4 bv = ((const float4*)b2)[q];
        float4 o;
        o.x = a0.x * dv + bv.x;
        o.y = a0.y * dv + bv.y;
        o.z = a0.z * dv + bv.z;
        o.w = a0.w * dv + bv.w;
        ((float4*)out)[(size_t)d * 8 + q] = o;
    }
}

extern "C" void kernel_launch(void* const* d_in, const int* in_sizes, int n_in,
                              void* d_out, int out_size, void* d_ws, size_t ws_size,
                              hipStream_t stream) {
    const float* x  = (const float*)d_in[0];
    const int*   ei = (const int*)d_in[1];
    const float* W1 = (const float*)d_in[2];
    const float* b1 = (const float*)d_in[3];
    const float* W2 = (const float*)d_in[4];
    const float* b2 = (const float*)d_in[5];

    int n = in_sizes[0] / F_IN;   // 50000
    int E = in_sizes[1] / 2;      // 800000
    const int* src = ei;
    const int* dst = ei + E;

    int nbuk  = (n + 255) >> 8;   // 196 (must be <= 256)
    int chunk = (E + NBLK - 1) / NBLK;

    char* ws = (char*)d_ws;
    size_t off = 0;
    auto alloc = [&](size_t bytes) {
        char* p = ws + off;
        off += (bytes + 255) & ~(size_t)255;
        return p;
    };
    int*   blockHist   = (int*)  alloc((size_t)NBLK * nbuk * 4);
    int*   blockOff    = (int*)  alloc((size_t)NBLK * nbuk * 4);
    int*   bucketTotal = (int*)  alloc((size_t)nbuk * 4);
    int*   bucketStart = (int*)  alloc((size_t)(nbuk + 1) * 4);
    int*   esort       = (int*)  alloc((size_t)E * 4);
    int*   col         = (int*)  alloc((size_t)E * 4);
    int*   rowstart    = (int*)  alloc((size_t)n * 4);
    int*   deg         = (int*)  alloc((size_t)n * 4);
    float* dis         = (float*)alloc((size_t)n * 4);
    float* g1          = (float*)alloc((size_t)n * F_MID * 4);
    float* h           = (float*)alloc((size_t)n * F_MID * 4);
    float* g2          = (float*)alloc((size_t)n * F_OUT * 4);

    k_hist<<<NBLK, 256, 0, stream>>>(dst, E, chunk, nbuk, blockHist);
    k_scan_buckets<<<nbuk, NBLK, 0, stream>>>(blockHist, nbuk, blockOff, bucketTotal);
    k_scan_starts<<<1, 256, 0, stream>>>(bucketTotal, nbuk, E, bucketStart);
    k_scatter_edges<<<NBLK, 256, 0, stream>>>(src, dst, E, chunk, nbuk, blockOff,
                                              bucketStart, esort);
    k_bucket_csr<<<nbuk, 256, 0, stream>>>(esort, bucketStart, n, rowstart, deg, dis, col);

    k_gemm1<<<(n + 63) / 64, 256, 0, stream>>>(x, W1, dis, g1, n);
    k_gather1<<<(n + 3) / 4, 256, 0, stream>>>(rowstart, deg, col, g1, dis, b1, h, n);
    k_gemm2<<<(n + 63) / 64, 256, 0, stream>>>(h, W2, dis, g2, n);
    k_gather2<<<(n + 3) / 4, 256, 0, stream>>>(rowstart, deg, col, g2, dis, b2,
                                               (float*)d_out, n);
}

// Round 8
// 184.719 us; speedup vs baseline: 1.8272x; 1.0646x over previous
//
#include <hip/hip_runtime.h>
#include <hip/hip_fp16.h>

// GCN 2-layer: x[N,128] -> GCNConv(W1[128,64]) -> relu -> GCNConv(W2[64,32])
// out[d] = dis[d] * (g[d] + sum_{e: dst=d} g[src]) + b,  g = (x@W)*dis.
// R7: g1/g2 tables stored fp16 (fp32 accumulate). Gather rows are 128 B / 64 B
//     -> half the cache lines & loads per neighbor (gathers are MLP-bound).

#define F_IN 128
#define F_MID 64
#define F_OUT 32
#define NBLK 256

#define RFL(x) __builtin_amdgcn_readfirstlane(x)

// add 8 halves (as uint4) into float a[8]
__device__ __forceinline__ void h8acc(float* a, const uint4& v) {
    const __half2* hp = (const __half2*)&v;
#pragma unroll
    for (int i = 0; i < 4; ++i) {
        float2 f = __half22float2(hp[i]);
        a[2 * i]     += f.x;
        a[2 * i + 1] += f.y;
    }
}

__device__ __forceinline__ uint4 pack8(const float4& a, const float4& b) {
    union { uint4 u; __half2 h[4]; } pk;
    pk.h[0] = __float22half2_rn(make_float2(a.x, a.y));
    pk.h[1] = __float22half2_rn(make_float2(a.z, a.w));
    pk.h[2] = __float22half2_rn(make_float2(b.x, b.y));
    pk.h[3] = __float22half2_rn(make_float2(b.z, b.w));
    return pk.u;
}

// ---- Pass A: per-block bucket histogram (bucket = dst >> 8) ----
__global__ __launch_bounds__(256) void k_hist(
    const int* __restrict__ dst, int E, int chunk, int nbuk,
    int* __restrict__ blockHist) {
    __shared__ int cnt[256];
    int t = threadIdx.x;
    cnt[t] = 0;
    __syncthreads();
    int e0 = blockIdx.x * chunk;
    int e1 = min(E, e0 + chunk);
    for (int e = e0 + t; e < e1; e += 256)
        atomicAdd(&cnt[dst[e] >> 8], 1);
    __syncthreads();
    if (t < nbuk) blockHist[blockIdx.x * nbuk + t] = cnt[t];
}

// ---- Pass B1: one block per bucket; parallel scan over the NBLK blocks ----
__global__ __launch_bounds__(NBLK) void k_scan_buckets(
    const int* __restrict__ blockHist, int nbuk,
    int* __restrict__ blockOff, int* __restrict__ bucketTotal) {
    __shared__ int s[NBLK];
    int b = blockIdx.x;
    int t = threadIdx.x;
    int v = blockHist[t * nbuk + b];
    s[t] = v;
    __syncthreads();
    for (int o = 1; o < NBLK; o <<= 1) {
        int add = (t >= o) ? s[t - o] : 0;
        __syncthreads();
        s[t] += add;
        __syncthreads();
    }
    blockOff[t * nbuk + b] = s[t] - v;      // exclusive within bucket
    if (t == NBLK - 1) bucketTotal[b] = s[t];
}

// ---- Pass B2: one tiny block; exclusive scan of bucket totals ----
__global__ __launch_bounds__(256) void k_scan_starts(
    const int* __restrict__ bucketTotal, int nbuk, int E,
    int* __restrict__ bucketStart) {
    __shared__ int s[256];
    int t = threadIdx.x;
    int v = (t < nbuk) ? bucketTotal[t] : 0;
    s[t] = v;
    __syncthreads();
    for (int o = 1; o < 256; o <<= 1) {
        int add = (t >= o) ? s[t - o] : 0;
        __syncthreads();
        s[t] += add;
        __syncthreads();
    }
    if (t < nbuk) bucketStart[t] = s[t] - v;
    if (t == 0) bucketStart[nbuk] = E;
}

// ---- Pass C: scatter packed (src<<8 | d&255) into bucket-ordered esort ----
__global__ __launch_bounds__(256) void k_scatter_edges(
    const int* __restrict__ src, const int* __restrict__ dst, int E, int chunk,
    int nbuk, const int* __restrict__ blockOff, const int* __restrict__ bucketStart,
    int* __restrict__ esort) {
    __shared__ int off[256];
    int t = threadIdx.x;
    if (t < nbuk) off[t] = blockOff[blockIdx.x * nbuk + t] + bucketStart[t];
    __syncthreads();
    int e0 = blockIdx.x * chunk;
    int e1 = min(E, e0 + chunk);
    for (int e = e0 + t; e < e1; e += 256) {
        int d = dst[e];
        int pos = atomicAdd(&off[d >> 8], 1);
        esort[pos] = (src[e] << 8) | (d & 255);   // src < 2^24
    }
}

// ---- Pass D: per-bucket exact CSR: deg, rowstart, dis, ordered col ----
__global__ __launch_bounds__(256) void k_bucket_csr(
    const int* __restrict__ esort, const int* __restrict__ bucketStart, int n,
    int* __restrict__ rowstart, int* __restrict__ deg, float* __restrict__ dis,
    int* __restrict__ col) {
    __shared__ int cnt[256];
    __shared__ int s[256];
    __shared__ int cur[256];
    int b = blockIdx.x;
    int t = threadIdx.x;
    int node0 = b << 8;
    int e0 = bucketStart[b], e1 = bucketStart[b + 1];
    cnt[t] = 0;
    __syncthreads();
    for (int e = e0 + t; e < e1; e += 256)
        atomicAdd(&cnt[esort[e] & 255], 1);
    __syncthreads();
    int v = cnt[t];
    s[t] = v;
    __syncthreads();
    for (int o = 1; o < 256; o <<= 1) {
        int add = (t >= o) ? s[t - o] : 0;
        __syncthreads();
        s[t] += add;
        __syncthreads();
    }
    int ex = s[t] - v;
    cur[t] = ex;
    int node = node0 + t;
    if (node < n) {
        rowstart[node] = e0 + ex;
        deg[node] = v;                       // in-degree (no self-loop)
        dis[node] = rsqrtf((float)(v + 1));  // +1 self-loop
    }
    __syncthreads();
    for (int e = e0 + t; e < e1; e += 256) {
        int p = esort[e];
        int pos = atomicAdd(&cur[p & 255], 1);
        col[e0 + pos] = p >> 8;              // src (non-negative)
    }
}

// g1h[r,f] = half((x[r,:] @ W1[:,f]) * dis[r])
// lane = row (64 rows/block), wave w -> features [16w, 16w+16)
__global__ __launch_bounds__(256, 4) void k_gemm1(
    const float* __restrict__ x, const float* __restrict__ W1,
    const float* __restrict__ dis, uint4* __restrict__ g1h, int n) {
    __shared__ float xs[64 * 129];   // pad 129: conflict-free
    int tid  = threadIdx.x;
    int row0 = blockIdx.x * 64;
    for (int i = tid; i < 64 * F_IN; i += 256) {
        int r = i >> 7, k = i & 127;
        int gr = row0 + r;
        xs[r * 129 + k] = (gr < n) ? x[(size_t)gr * F_IN + k] : 0.0f;
    }
    __syncthreads();
    int w = RFL(tid >> 6);
    int r = tid & 63;
    const float4* W4 = (const float4*)W1;   // [128][16] float4 view
    float4 a0 = {0.f,0.f,0.f,0.f}, a1 = a0, a2 = a0, a3 = a0;
#pragma unroll 4
    for (int k = 0; k < F_IN; ++k) {
        float xv = xs[r * 129 + k];
        float4 w0 = W4[k * 16 + w * 4 + 0];
        float4 w1 = W4[k * 16 + w * 4 + 1];
        float4 w2 = W4[k * 16 + w * 4 + 2];
        float4 w3 = W4[k * 16 + w * 4 + 3];
        a0.x += xv * w0.x; a0.y += xv * w0.y; a0.z += xv * w0.z; a0.w += xv * w0.w;
        a1.x += xv * w1.x; a1.y += xv * w1.y; a1.z += xv * w1.z; a1.w += xv * w1.w;
        a2.x += xv * w2.x; a2.y += xv * w2.y; a2.z += xv * w2.z; a2.w += xv * w2.w;
        a3.x += xv * w3.x; a3.y += xv * w3.y; a3.z += xv * w3.z; a3.w += xv * w3.w;
    }
    int gr = row0 + r;
    if (gr < n) {
        float dv = dis[gr];
        a0.x *= dv; a0.y *= dv; a0.z *= dv; a0.w *= dv;
        a1.x *= dv; a1.y *= dv; a1.z *= dv; a1.w *= dv;
        a2.x *= dv; a2.y *= dv; a2.z *= dv; a2.w *= dv;
        a3.x *= dv; a3.y *= dv; a3.z *= dv; a3.w *= dv;
        g1h[(size_t)gr * 8 + w * 2 + 0] = pack8(a0, a1);
        g1h[(size_t)gr * 8 + w * 2 + 1] = pack8(a2, a3);
    }
}

// one wave per dst row. fp16 row = 128 B = 8 x uint4. lane: q=lane&7 (chunk),
// slot=lane>>3 (neighbor). One dwordx4 instr fetches 8 neighbor rows.
__global__ __launch_bounds__(256) void k_gather1(
    const int* __restrict__ rowstart, const int* __restrict__ deg,
    const int* __restrict__ col, const uint4* __restrict__ g1h,
    const float* __restrict__ dis, const float* __restrict__ b1,
    float* __restrict__ h, int n) {
    int wave = RFL(threadIdx.x >> 6);
    int lane = threadIdx.x & 63;
    int q    = lane & 7;    // features 8q..8q+7
    int slot = lane >> 3;   // 0..7
    int d    = blockIdx.x * 4 + wave;
    if (d >= n) return;
    int base = RFL(rowstart[d]);
    int cnt  = RFL(deg[d]);
    float a[8] = {0,0,0,0,0,0,0,0};
    float b[8] = {0,0,0,0,0,0,0,0};
    if (slot == 0) {                       // self-loop
        uint4 v = g1h[(size_t)d * 8 + q];
        h8acc(a, v);
    }
    int j = 0;
    for (; j + 16 <= cnt; j += 16) {
        int s0 = col[base + j + slot];
        int s1 = col[base + j + 8 + slot];
        uint4 v0 = g1h[(size_t)s0 * 8 + q];
        uint4 v1 = g1h[(size_t)s1 * 8 + q];
        h8acc(a, v0);
        h8acc(b, v1);
    }
    for (; j + 8 <= cnt; j += 8) {
        int s = col[base + j + slot];
        uint4 v = g1h[(size_t)s * 8 + q];
        h8acc(a, v);
    }
    if (slot < cnt - j) {
        int s = col[base + j + slot];
        uint4 v = g1h[(size_t)s * 8 + q];
        h8acc(a, v);
    }
#pragma unroll
    for (int i = 0; i < 8; ++i) a[i] += b[i];
#pragma unroll
    for (int i = 0; i < 8; ++i) a[i] += __shfl_xor(a[i], 8);
#pragma unroll
    for (int i = 0; i < 8; ++i) a[i] += __shfl_xor(a[i], 16);
#pragma unroll
    for (int i = 0; i < 8; ++i) a[i] += __shfl_xor(a[i], 32);
    if (slot == 0) {
        float dv = dis[d];
        float4 bv0 = ((const float4*)b1)[q * 2 + 0];
        float4 bv1 = ((const float4*)b1)[q * 2 + 1];
        float4 o0, o1;
        o0.x = fmaxf(a[0] * dv + bv0.x, 0.f);
        o0.y = fmaxf(a[1] * dv + bv0.y, 0.f);
        o0.z = fmaxf(a[2] * dv + bv0.z, 0.f);
        o0.w = fmaxf(a[3] * dv + bv0.w, 0.f);
        o1.x = fmaxf(a[4] * dv + bv1.x, 0.f);
        o1.y = fmaxf(a[5] * dv + bv1.y, 0.f);
        o1.z = fmaxf(a[6] * dv + bv1.z, 0.f);
        o1.w = fmaxf(a[7] * dv + bv1.w, 0.f);
        float4* H4 = (float4*)h;
        H4[(size_t)d * 16 + q * 2 + 0] = o0;
        H4[(size_t)d * 16 + q * 2 + 1] = o1;
    }
}

// g2h[r,j] = half((h[r,:] @ W2[:,j]) * dis[r])
// lane = row (64 rows/block), wave w -> features [8w, 8w+8)
__global__ __launch_bounds__(256, 4) void k_gemm2(
    const float* __restrict__ h, const float* __restrict__ W2,
    const float* __restrict__ dis, uint4* __restrict__ g2h, int n) {
    __shared__ float hs[64 * 65];    // pad 65: conflict-free
    int tid  = threadIdx.x;
    int row0 = blockIdx.x * 64;
    for (int i = tid; i < 64 * F_MID; i += 256) {
        int r = i >> 6, k = i & 63;
        int gr = row0 + r;
        hs[r * 65 + k] = (gr < n) ? h[(size_t)gr * F_MID + k] : 0.0f;
    }
    __syncthreads();
    int w = RFL(tid >> 6);
    int r = tid & 63;
    const float4* W4 = (const float4*)W2;   // [64][8] float4 view
    float4 a0 = {0.f,0.f,0.f,0.f}, a1 = a0;
#pragma unroll 4
    for (int k = 0; k < F_MID; ++k) {
        float hv = hs[r * 65 + k];
        float4 w0 = W4[k * 8 + w * 2 + 0];
        float4 w1 = W4[k * 8 + w * 2 + 1];
        a0.x += hv * w0.x; a0.y += hv * w0.y; a0.z += hv * w0.z; a0.w += hv * w0.w;
        a1.x += hv * w1.x; a1.y += hv * w1.y; a1.z += hv * w1.z; a1.w += hv * w1.w;
    }
    int gr = row0 + r;
    if (gr < n) {
        float dv = dis[gr];
        a0.x *= dv; a0.y *= dv; a0.z *= dv; a0.w *= dv;
        a1.x *= dv; a1.y *= dv; a1.z *= dv; a1.w *= dv;
        g2h[(size_t)gr * 4 + w] = pack8(a0, a1);
    }
}

// one wave per dst row. fp16 row = 64 B = 4 x uint4. q=lane&3, slot=lane>>2.
// One dwordx4 instr fetches 16 neighbor rows.
__global__ __launch_bounds__(256) void k_gather2(
    const int* __restrict__ rowstart, const int* __restrict__ deg,
    const int* __restrict__ col, const uint4* __restrict__ g2h,
    const float* __restrict__ dis, const float* __restrict__ b2,
    float* __restrict__ out, int n) {
    int wave = RFL(threadIdx.x >> 6);
    int lane = threadIdx.x & 63;
    int q    = lane & 3;    // features 8q..8q+7
    int slot = lane >> 2;   // 0..15
    int d    = blockIdx.x * 4 + wave;
    if (d >= n) return;
    int base = RFL(rowstart[d]);
    int cnt  = RFL(deg[d]);
    float a[8] = {0,0,0,0,0,0,0,0};
    float b[8] = {0,0,0,0,0,0,0,0};
    if (slot == 0) {                       // self-loop
        uint4 v = g2h[(size_t)d * 4 + q];
        h8acc(a, v);
    }
    int j = 0;
    for (; j + 32 <= cnt; j += 32) {
        int s0 = col[base + j + slot];
        int s1 = col[base + j + 16 + slot];
        uint4 v0 = g2h[(size_t)s0 * 4 + q];
        uint4 v1 = g2h[(size_t)s1 * 4 + q];
        h8acc(a, v0);
        h8acc(b, v1);
    }
    for (; j + 16 <= cnt; j += 16) {
        int s = col[base + j + slot];
        uint4 v = g2h[(size_t)s * 4 + q];
        h8acc(a, v);
    }
    if (slot < cnt - j) {
        int s = col[base + j + slot];
        uint4 v = g2h[(size_t)s * 4 + q];
        h8acc(a, v);
    }
#pragma unroll
    for (int i = 0; i < 8; ++i) a[i] += b[i];
#pragma unroll
    for (int i = 0; i < 8; ++i) a[i] += __shfl_xor(a[i], 4);
#pragma unroll
    for (int i = 0; i < 8; ++i) a[i] += __shfl_xor(a[i], 8);
#pragma unroll
    for (int i = 0; i < 8; ++i) a[i] += __shfl_xor(a[i], 16);
#pragma unroll
    for (int i = 0; i < 8; ++i) a[i] += __shfl_xor(a[i], 32);
    if (slot == 0) {
        float dv = dis[d];
        float4 bv0 = ((const float4*)b2)[q * 2 + 0];
        float4 bv1 = ((const float4*)b2)[q * 2 + 1];
        float4 o0, o1;
        o0.x = a[0] * dv + bv0.x;
        o0.y = a[1] * dv + bv0.y;
        o0.z = a[2] * dv + bv0.z;
        o0.w = a[3] * dv + bv0.w;
        o1.x = a[4] * dv + bv1.x;
        o1.y = a[5] * dv + bv1.y;
        o1.z = a[6] * dv + bv1.z;
        o1.w = a[7] * dv + bv1.w;
        float4* O4 = (float4*)out;
        O4[(size_t)d * 8 + q * 2 + 0] = o0;
        O4[(size_t)d * 8 + q * 2 + 1] = o1;
    }
}

extern "C" void kernel_launch(void* const* d_in, const int* in_sizes, int n_in,
                              void* d_out, int out_size, void* d_ws, size_t ws_size,
                              hipStream_t stream) {
    const float* x  = (const float*)d_in[0];
    const int*   ei = (const int*)d_in[1];
    const float* W1 = (const float*)d_in[2];
    const float* b1 = (const float*)d_in[3];
    const float* W2 = (const float*)d_in[4];
    const float* b2 = (const float*)d_in[5];

    int n = in_sizes[0] / F_IN;   // 50000
    int E = in_sizes[1] / 2;      // 800000
    const int* src = ei;
    const int* dst = ei + E;

    int nbuk  = (n + 255) >> 8;   // 196 (must be <= 256)
    int chunk = (E + NBLK - 1) / NBLK;

    char* ws = (char*)d_ws;
    size_t off = 0;
    auto alloc = [&](size_t bytes) {
        char* p = ws + off;
        off += (bytes + 255) & ~(size_t)255;
        return p;
    };
    int*   blockHist   = (int*)  alloc((size_t)NBLK * nbuk * 4);
    int*   blockOff    = (int*)  alloc((size_t)NBLK * nbuk * 4);
    int*   bucketTotal = (int*)  alloc((size_t)nbuk * 4);
    int*   bucketStart = (int*)  alloc((size_t)(nbuk + 1) * 4);
    int*   esort       = (int*)  alloc((size_t)E * 4);
    int*   col         = (int*)  alloc((size_t)E * 4);
    int*   rowstart    = (int*)  alloc((size_t)n * 4);
    int*   deg         = (int*)  alloc((size_t)n * 4);
    float* dis         = (float*)alloc((size_t)n * 4);
    uint4* g1h         = (uint4*)alloc((size_t)n * F_MID * 2);   // fp16
    float* h           = (float*)alloc((size_t)n * F_MID * 4);   // fp32
    uint4* g2h         = (uint4*)alloc((size_t)n * F_OUT * 2);   // fp16

    k_hist<<<NBLK, 256, 0, stream>>>(dst, E, chunk, nbuk, blockHist);
    k_scan_buckets<<<nbuk, NBLK, 0, stream>>>(blockHist, nbuk, blockOff, bucketTotal);
    k_scan_starts<<<1, 256, 0, stream>>>(bucketTotal, nbuk, E, bucketStart);
    k_scatter_edges<<<NBLK, 256, 0, stream>>>(src, dst, E, chunk, nbuk, blockOff,
                                              bucketStart, esort);
    k_bucket_csr<<<nbuk, 256, 0, stream>>>(esort, bucketStart, n, rowstart, deg, dis, col);

    k_gemm1<<<(n + 63) / 64, 256, 0, stream>>>(x, W1, dis, g1h, n);
    k_gather1<<<(n + 3) / 4, 256, 0, stream>>>(rowstart, deg, col, g1h, dis, b1, h, n);
    k_gemm2<<<(n + 63) / 64, 256, 0, stream>>>(h, W2, dis, g2h, n);
    k_gather2<<<(n + 3) / 4, 256, 0, stream>>>(rowstart, deg, col, g2h, dis, b2,
                                               (float*)d_out, n);
}